// Round 3
// baseline (322.337 us; speedup 1.0000x reference)
//
#include <hip/hip_runtime.h>
#include <hip/hip_bf16.h>

#define NN 50000
#define EE 800000
#define OUTD 40
#define NBUCK 196   // dst >> 8 buckets (50000/256 -> 0..195)
#define BCAP 8192   // slots per bucket (avg fill ~4082)
#define ABLKS 400   // scatter blocks (>= 1.5 per CU)
#define EPB 2000    // edges per scatter block

typedef __attribute__((ext_vector_type(8))) short short8;
typedef __attribute__((ext_vector_type(4))) float floatx4;

__device__ __forceinline__ float bf2f(unsigned short u) {
  union { unsigned int i; float f; } v; v.i = ((unsigned int)u) << 16; return v.f;
}
__device__ __forceinline__ unsigned short f2bf(float f) {
  union { float f; unsigned int i; } v; v.f = f;
  unsigned int x = v.i;
  return (unsigned short)((x + 0x7fffu + ((x >> 16) & 1u)) >> 16);  // RNE, finite-only
}
__device__ __forceinline__ float blo(unsigned int u) {
  union { unsigned int i; float f; } v; v.i = u << 16; return v.f;
}
__device__ __forceinline__ float bhi(unsigned int u) {
  union { unsigned int i; float f; } v; v.i = u & 0xffff0000u; return v.f;
}

template <int CTRL>
__device__ __forceinline__ float dpp_add(float x) {
  int y = __builtin_amdgcn_update_dpp(0, __float_as_int(x), CTRL, 0xF, 0xF, true);
  return x + __int_as_float(y);
}

// tanh-approx GELU (max abs err ~1e-3, well inside bf16 tolerance)
__device__ __forceinline__ float gelu1(float y) {
  float y2 = y * y;
  float z = y * fmaf(0.0356774081f, y2, 0.7978845608f);
  float e = __expf(-2.f * z);
  float r = __builtin_amdgcn_rcpf(1.f + e);
  float th = fmaf(2.f, r, -1.f);
  return y * fmaf(0.5f, th, 0.5f);
}

// clamp edge index into [0, last]
__device__ __forceinline__ int clampe(int i, int last) {
  int r = i <= last ? i : last;
  return r < 0 ? 0 : r;
}

// wave-local dtype probes (same 512B window everywhere -> identical result)
__device__ __forceinline__ int probe_f32(const void* x) {
  int lane = threadIdx.x & 63;
  unsigned short u = ((const unsigned short*)x)[2 * lane];
  int exf = (u >> 7) & 0xFF;
  unsigned long long b = __ballot((exf >= 100 && exf <= 142) ? 1 : 0);
  return (__popcll(b) >= 48) ? 0 : 1;
}
__device__ __forceinline__ int probe_i64(const void* ei) {
  int lane = threadIdx.x & 63;
  long long v = ((const long long*)ei)[lane];
  unsigned long long b = __ballot((v >= 0 && v < NN) ? 1 : 0);
  return (__popcll(b) >= 48) ? 1 : 0;
}

// ---------------- weight rearrange + param convert descriptors ----------------
struct WDesc { const void* W; unsigned short* F; int T; int ncols; };
struct WDescs { WDesc d[7]; int cum[8]; };
struct PCv { const void* s; unsigned short* d; int n; int cap; };
struct PCvs { PCv a[17]; };

// ---------------- init: weights + params + flags + bucket-cursor zero ----------------
__global__ __launch_bounds__(256) void init_kernel(const void* __restrict__ ei,
                                                   const void* __restrict__ x,
                                                   int* __restrict__ flags,
                                                   int* __restrict__ bcur,
                                                   WDescs ds, PCvs P) {
  int b = blockIdx.x;
  int f32 = probe_f32(x);
  if (b < 48) {
    int idx = b * 256 + threadIdx.x;
    if (idx >= 12288) return;
    int mi = 0;
    while (idx >= ds.cum[mi + 1]) mi++;
    int local = idx - ds.cum[mi];
    WDesc d = ds.d[mi];
    int lane = local & 63;
    int rest = local >> 6;
    int t = rest % d.T;
    int kb = rest / d.T;
    int m = lane & 15, quad = lane >> 4;
    int col = t * 16 + m;
    short8 v;
    for (int j = 0; j < 8; ++j) {
      int k = kb * 32 + quad * 8 + j;
      if (col < d.ncols) {
        int off = k * d.ncols + col;
        v[j] = f32 ? (short)f2bf(((const float*)d.W)[off])
                   : (short)((const unsigned short*)d.W)[off];
      } else {
        v[j] = 0;
      }
    }
    *(short8*)(d.F + (size_t)local * 8) = v;
  } else if (b < 65) {
    PCv p = P.a[b - 48];
    for (int i = threadIdx.x; i < p.cap; i += 256) {
      unsigned short o = 0;
      if (i < p.n)
        o = f32 ? f2bf(((const float*)p.s)[i]) : ((const unsigned short*)p.s)[i];
      p.d[i] = o;
    }
  } else {
    for (int i = threadIdx.x; i < NBUCK * 16; i += 256) bcur[i] = 0;
    if (threadIdx.x < 64) {
      int i64 = probe_i64(ei);
      if (threadIdx.x == 0) {
        flags[0] = i64;
        flags[1] = f32;
        flags[2] = 0;
      }
    }
  }
}

// ---------------- multi-output GEMM body: Out_i[M,ncols] = A[M,128] @ W_i + b_i ----
// Operand-SWAPPED MFMA: mfma(w_frag, a_frag) transposes the D-tile so lane
// (quad,m) holds row r0+m, cols t*16+quad*4..+3 in acc[0..3] -> one packed
// uint2 (8B) store per lane per t (4x fewer store insts, 32B segments kept).
struct GSet { const unsigned short* F; const unsigned short* bias; unsigned short* Out; };
struct GArgs { GSet s[3]; };

__device__ __forceinline__ short8 pack_f4(float4 u0, float4 u1) {
  short8 r;
  r[0] = (short)f2bf(u0.x); r[1] = (short)f2bf(u0.y);
  r[2] = (short)f2bf(u0.z); r[3] = (short)f2bf(u0.w);
  r[4] = (short)f2bf(u1.x); r[5] = (short)f2bf(u1.y);
  r[6] = (short)f2bf(u1.z); r[7] = (short)f2bf(u1.w);
  return r;
}

__device__ __forceinline__ void gemm_body(int wave, int lane, const void* __restrict__ A,
                                          int f32, const GArgs& g, int nset, int M,
                                          int T, int ncols,
                                          unsigned short* __restrict__ Acache) {
  int r0 = wave * 16;
  if (r0 >= M) return;
  int m = lane & 15, quad = lane >> 4;
  short8 a0, a1, a2, a3;
  if (!f32) {
    const unsigned short* ar = (const unsigned short*)A + (size_t)(r0 + m) * 128 + quad * 8;
    a0 = *(const short8*)(ar);
    a1 = *(const short8*)(ar + 32);
    a2 = *(const short8*)(ar + 64);
    a3 = *(const short8*)(ar + 96);
  } else {
    const float* ar = (const float*)A + (size_t)(r0 + m) * 128 + quad * 8;
    a0 = pack_f4(*(const float4*)(ar), *(const float4*)(ar + 4));
    a1 = pack_f4(*(const float4*)(ar + 32), *(const float4*)(ar + 36));
    a2 = pack_f4(*(const float4*)(ar + 64), *(const float4*)(ar + 68));
    a3 = pack_f4(*(const float4*)(ar + 96), *(const float4*)(ar + 100));
    if (Acache) {  // one-time bf16 A cache for later passes (coalesced 16B/lane)
      unsigned short* cp = Acache + (size_t)(r0 + m) * 128 + quad * 8;
      *(short8*)(cp) = a0;
      *(short8*)(cp + 32) = a1;
      *(short8*)(cp + 64) = a2;
      *(short8*)(cp + 96) = a3;
    }
  }
  size_t kstride = (size_t)T * 64 * 8;
  for (int si = 0; si < nset; ++si) {
    const unsigned short* F = g.s[si].F;
    const unsigned short* bias = g.s[si].bias;
    unsigned short* Out = g.s[si].Out;
    for (int t = 0; t < T; ++t) {
      floatx4 acc = {0.f, 0.f, 0.f, 0.f};
      const unsigned short* wp = F + ((size_t)t * 64 + lane) * 8;
      acc = __builtin_amdgcn_mfma_f32_16x16x32_bf16(*(const short8*)(wp), a0, acc, 0, 0, 0);
      acc = __builtin_amdgcn_mfma_f32_16x16x32_bf16(*(const short8*)(wp + kstride), a1, acc, 0, 0, 0);
      acc = __builtin_amdgcn_mfma_f32_16x16x32_bf16(*(const short8*)(wp + 2 * kstride), a2, acc, 0, 0, 0);
      acc = __builtin_amdgcn_mfma_f32_16x16x32_bf16(*(const short8*)(wp + 3 * kstride), a3, acc, 0, 0, 0);
      int cbase = t * 16 + quad * 4;
      if (cbase < ncols) {  // ncols % 4 == 0 -> whole quad valid
        uint2 bb = *(const uint2*)(bias + cbase);
        float v0 = acc[0] + blo(bb.x), v1 = acc[1] + bhi(bb.x);
        float v2 = acc[2] + blo(bb.y), v3 = acc[3] + bhi(bb.y);
        uint2 pk;
        pk.x = (unsigned int)f2bf(v0) | ((unsigned int)f2bf(v1) << 16);
        pk.y = (unsigned int)f2bf(v2) | ((unsigned int)f2bf(v3) << 16);
        *(uint2*)(Out + (size_t)(r0 + m) * ncols + cbase) = pk;
      }
    }
  }
}

// standalone GEMM (layers 2/3): 256 threads, 4 waves/block
__global__ __launch_bounds__(256) void gemm_multi_kernel(
    const void* __restrict__ A, const int* __restrict__ flagp, GArgs g,
    int nset, int M, int T, int ncols) {
  int wave = blockIdx.x * 4 + (threadIdx.x >> 6);
  int lane = threadIdx.x & 63;
  gemm_body(wave, lane, A, *flagp, g, nset, M, T, ncols, nullptr);
}

// ---------------- fused: scatter (blocks < ABLKS) || layer-1 identity GEMM ----------
__global__ __launch_bounds__(512) void fused_scatter_gemm(
    const void* __restrict__ ei, unsigned int* __restrict__ bedges,
    int* __restrict__ bcur, const void* __restrict__ A,
    const int* __restrict__ flagp, GArgs g, int nset, int M, int T, int ncols,
    unsigned short* __restrict__ Acache) {
  __shared__ int lhist[NBUCK];
  __shared__ int lbase[NBUCK];
  if (blockIdx.x >= ABLKS) {
    int wave = (blockIdx.x - ABLKS) * 8 + (threadIdx.x >> 6);
    int f32 = *flagp;
    gemm_body(wave, threadIdx.x & 63, A, f32, g, nset, M, T, ncols,
              f32 ? Acache : nullptr);
    return;
  }
  int tid = threadIdx.x;
  if (tid < NBUCK) lhist[tid] = 0;
  int i64 = probe_i64(ei);
  __syncthreads();
  int e0 = blockIdx.x * EPB;
  int e1 = e0 + EPB; if (e1 > EE) e1 = EE;
  // phase 1: local histogram of dst bins
  for (int e = e0 + tid; e < e1; e += 512) {
    int d = i64 ? (int)((const long long*)ei)[EE + e] : ((const int*)ei)[EE + e];
    d = d < 0 ? 0 : (d >= NN ? NN - 1 : d);
    atomicAdd(&lhist[d >> 8], 1);
  }
  __syncthreads();
  // phase 2: one global reservation per bin
  if (tid < NBUCK) {
    int c = lhist[tid];
    lbase[tid] = c ? atomicAdd(&bcur[tid * 16], c) : 0;  // cursors padded to 64B
    lhist[tid] = 0;                                      // reuse as local cursor
  }
  __syncthreads();
  // phase 3: ranked scatter
  for (int e = e0 + tid; e < e1; e += 512) {
    int s, d;
    if (i64) {
      s = (int)((const long long*)ei)[e];
      d = (int)((const long long*)ei)[EE + e];
    } else {
      s = ((const int*)ei)[e];
      d = ((const int*)ei)[EE + e];
    }
    s = s < 0 ? 0 : (s >= NN ? NN - 1 : s);
    d = d < 0 ? 0 : (d >= NN ? NN - 1 : d);
    int bin = d >> 8;
    int r = atomicAdd(&lhist[bin], 1);
    int pos = lbase[bin] + r;
    if (pos < BCAP)
      bedges[(size_t)bin * BCAP + pos] =
          ((unsigned int)(d & 0xFF) << 24) | ((unsigned int)s << 8);
  }
}

// ---------------- fused: per-bucket dst sort (blocks < NBUCK) || layer-1 l/r GEMM ----
__global__ __launch_bounds__(512) void fused_sort_gemm(
    const unsigned int* __restrict__ bedges, const int* __restrict__ bcur,
    int* __restrict__ offs, int* __restrict__ src_sorted,
    const void* __restrict__ A, const int* __restrict__ flagp, GArgs g,
    int nset, int M, int T, int ncols, const unsigned short* __restrict__ Acache) {
  __shared__ int lhist[256];
  __shared__ int lscan[256];
  __shared__ int lbin[256];
  __shared__ int sbase, scount, stotal;
  __shared__ unsigned int le[BCAP];
  __shared__ unsigned short lrank[BCAP];
  if (blockIdx.x >= NBUCK) {
    int wave = (blockIdx.x - NBUCK) * 8 + (threadIdx.x >> 6);
    int f32 = *flagp;
    // pass 1 cached bf16 A when input was f32 -> always bf16 path here
    const void* Ause = f32 ? (const void*)Acache : A;
    gemm_body(wave, threadIdx.x & 63, Ause, 0, g, nset, M, T, ncols, nullptr);
    return;
  }
  int k = blockIdx.x;
  int tid = threadIdx.x;
  if (tid < 256) {
    int c = 0;
    if (tid < NBUCK) {
      int v = bcur[tid * 16];
      c = v < BCAP ? v : BCAP;
    }
    lscan[tid] = c;
  }
  __syncthreads();
  for (int off = 1; off < 256; off <<= 1) {
    int u = 0;
    if (tid < 256 && tid >= off) u = lscan[tid - off];
    __syncthreads();
    if (tid < 256) lscan[tid] += u;
    __syncthreads();
  }
  if (tid == 0) {
    int pb = (k == 0) ? 0 : lscan[k - 1];
    sbase = pb;
    scount = lscan[k] - pb;
    stotal = lscan[NBUCK - 1];
  }
  if (tid < 256) lhist[tid] = 0;
  __syncthreads();
  int base = sbase, count = scount;
  const unsigned int* myb = bedges + (size_t)k * BCAP;
  for (int i = tid; i < count; i += 512) {
    unsigned int pk = myb[i];
    int bin = pk >> 24;
    int r = atomicAdd(&lhist[bin], 1);
    le[i] = pk;
    lrank[i] = (unsigned short)r;
  }
  __syncthreads();
  int hc = 0;
  if (tid < 256) {
    hc = lhist[tid];
    lscan[tid] = hc;
  }
  __syncthreads();
  for (int off = 1; off < 256; off <<= 1) {
    int u = 0;
    if (tid < 256 && tid >= off) u = lscan[tid - off];
    __syncthreads();
    if (tid < 256) lscan[tid] += u;
    __syncthreads();
  }
  if (tid < 256) {
    int binoff = lscan[tid] - hc;  // exclusive within bucket
    lbin[tid] = binoff;
    int node = k * 256 + tid;
    if (node < NN) offs[node] = base + binoff;
    if (k == 0 && tid == 0) offs[NN] = stotal;
  }
  __syncthreads();
  for (int i = tid; i < count; i += 512) {
    unsigned int pk = le[i];
    int bin = pk >> 24;
    int pos = base + lbin[bin] + (int)lrank[i];
    src_sorted[pos] = (int)(pk & 0x00FFFF00u);  // src<<8 byte offset
  }
}

// ---------------- edge aggregation, hidden layers (H=4, C=32) ----------------
// At the compulsory cross-XCD L2-fill roofline (~90 MB fills @ ~2.3 TB/s) — leave as-is.
__global__ __launch_bounds__(256) void edge_hid_kernel(
    const unsigned short* __restrict__ xl, const unsigned short* __restrict__ xr,
    const unsigned short* __restrict__ att, const unsigned short* __restrict__ bias,
    const unsigned short* __restrict__ gamma, const unsigned short* __restrict__ beta,
    const unsigned short* __restrict__ resid, unsigned short* __restrict__ xout,
    const int* __restrict__ offs, const int* __restrict__ srcs) {
  int wpair = blockIdx.x * 4 + (threadIdx.x >> 6);
  int lane = threadIdx.x & 63;
  int half = lane >> 5;
  int wv = wpair * 2 + half;
  if (wv >= NN) return;
  int hl = lane & 31;
  int sub = hl >> 4;          // edge slot (0/1) within this half
  int cb = (hl & 15) * 16;    // byte offset of this lane's 8 channels (256 B/row)
  int beg = offs[wv], end = offs[wv + 1], last = end - 1;
  int iters = (end - beg + 1) >> 1;  // ceil(deg/2)
  int oi = __shfl_xor(iters, 32);
  int maxit = __builtin_amdgcn_readfirstlane(iters > oi ? iters : oi);
  const char* xlb = (const char*)xl;
  int c0 = hl * 4;
  // hoisted epilogue load: resid row latency hides under the whole edge loop
  uint2 rr = *(const uint2*)(resid + (size_t)wv * 128 + c0);
  uint4 xr8 = *(const uint4*)((const char*)xr + (size_t)wv * 256 + cb);
  float rx0 = blo(xr8.x), rx1 = bhi(xr8.x), rx2 = blo(xr8.y), rx3 = bhi(xr8.y);
  float rx4 = blo(xr8.z), rx5 = bhi(xr8.z), rx6 = blo(xr8.w), rx7 = bhi(xr8.w);
  uint4 at8 = *(const uint4*)((const char*)att + cb);
  float a0 = blo(at8.x), a1 = bhi(at8.x), a2 = blo(at8.y), a3 = bhi(at8.y);
  float a4 = blo(at8.z), a5 = bhi(at8.z), a6 = blo(at8.w), a7 = bhi(at8.w);
  float acc0 = 0.f, acc1 = 0.f, acc2 = 0.f, acc3 = 0.f;
  float acc4 = 0.f, acc5 = 0.f, acc6 = 0.f, acc7 = 0.f, den = 0.f;
  // pipeline prologue: index for edge 0 and edge 1, gather for edge 0
  int ir = beg + sub;
  int o_cur = srcs[clampe(ir, last)];
  int o_nxt = srcs[clampe(ir + 2, last)];
  uint4 u = *(const uint4*)(xlb + (o_cur + cb));
  for (int it = 0; it < maxit; ++it) {
    int o_p = srcs[clampe(ir + 4, last)];
    uint4 un = *(const uint4*)(xlb + (o_nxt + cb));
    float mk = (ir <= last) ? 1.f : 0.f;
    ir += 2;
    float x0 = blo(u.x), x1 = bhi(u.x), x2 = blo(u.y), x3 = bhi(u.y);
    float x4 = blo(u.z), x5 = bhi(u.z), x6 = blo(u.w), x7 = bhi(u.w);
    float t0 = x0 + rx0, t1 = x1 + rx1, t2 = x2 + rx2, t3 = x3 + rx3;
    float t4 = x4 + rx4, t5 = x5 + rx5, t6 = x6 + rx6, t7 = x7 + rx7;
    float pa = a0 * t0;
    pa = fmaf(a1, t1, pa); pa = fmaf(a2, t2, pa); pa = fmaf(a3, t3, pa);
    pa = fmaf(a4, t4, pa); pa = fmaf(a5, t5, pa); pa = fmaf(a6, t6, pa); pa = fmaf(a7, t7, pa);
    float pb = a0 * fabsf(t0);
    pb = fmaf(a1, fabsf(t1), pb); pb = fmaf(a2, fabsf(t2), pb); pb = fmaf(a3, fabsf(t3), pb);
    pb = fmaf(a4, fabsf(t4), pb); pb = fmaf(a5, fabsf(t5), pb);
    pb = fmaf(a6, fabsf(t6), pb); pb = fmaf(a7, fabsf(t7), pb);
    float p = fmaf(0.4f, pb, 0.6f * pa);
    p = dpp_add<0xB1>(p);  // quad xor1
    p = dpp_add<0x4E>(p);  // quad xor2 -> 4-lane head sum (32 ch)
    float w = __expf(fminf(p, 60.f)) * mk;
    den += w;
    acc0 = fmaf(w, x0, acc0); acc1 = fmaf(w, x1, acc1);
    acc2 = fmaf(w, x2, acc2); acc3 = fmaf(w, x3, acc3);
    acc4 = fmaf(w, x4, acc4); acc5 = fmaf(w, x5, acc5);
    acc6 = fmaf(w, x6, acc6); acc7 = fmaf(w, x7, acc7);
    u = un;
    o_nxt = o_p;
  }
  // merge the two edge slots within each half (xor16 stays inside the half)
  den += __shfl_xor(den, 16);
  acc0 += __shfl_xor(acc0, 16); acc1 += __shfl_xor(acc1, 16);
  acc2 += __shfl_xor(acc2, 16); acc3 += __shfl_xor(acc3, 16);
  acc4 += __shfl_xor(acc4, 16); acc5 += __shfl_xor(acc5, 16);
  acc6 += __shfl_xor(acc6, 16); acc7 += __shfl_xor(acc7, 16);
  // redistribute to 4 ch/lane within each half (32 lanes per dst)
  int srcLane = (half << 5) + (hl >> 1);
  float b0 = __shfl(acc0, srcLane), b1 = __shfl(acc1, srcLane);
  float b2 = __shfl(acc2, srcLane), b3 = __shfl(acc3, srcLane);
  float h4 = __shfl(acc4, srcLane), h5 = __shfl(acc5, srcLane);
  float h6 = __shfl(acc6, srcLane), h7 = __shfl(acc7, srcLane);
  float dn = __shfl(den, srcLane);
  bool hi = (hl & 1) != 0;
  float v0 = hi ? h4 : b0, v1 = hi ? h5 : b1, v2 = hi ? h6 : b2, v3 = hi ? h7 : b3;
  float inv = __builtin_amdgcn_rcpf(dn + 1e-16f);
  uint2 bb = *(const uint2*)(bias + c0);
  float o0 = v0 * inv + blo(bb.x), o1 = v1 * inv + bhi(bb.x);
  float o2 = v2 * inv + blo(bb.y), o3 = v3 * inv + bhi(bb.y);
  // LayerNorm over 128 ch: 32-lane reduction within each half
  float s = (o0 + o1) + (o2 + o3);
  for (int k = 1; k < 32; k <<= 1) s += __shfl_xor(s, k);
  float mu = s * (1.f / 128.f);
  float d0 = o0 - mu, d1 = o1 - mu, d2 = o2 - mu, d3 = o3 - mu;
  float q = (d0 * d0 + d1 * d1) + (d2 * d2 + d3 * d3);
  for (int k = 1; k < 32; k <<= 1) q += __shfl_xor(q, k);
  float rstd = rsqrtf(q * (1.f / 128.f) + 1e-5f);
  uint2 gg = *(const uint2*)(gamma + c0);
  uint2 be = *(const uint2*)(beta + c0);
  float y0 = d0 * rstd * blo(gg.x) + blo(be.x);
  float y1 = d1 * rstd * bhi(gg.x) + bhi(be.x);
  float y2 = d2 * rstd * blo(gg.y) + blo(be.y);
  float y3 = d3 * rstd * bhi(gg.y) + bhi(be.y);
  y0 = gelu1(y0); y1 = gelu1(y1); y2 = gelu1(y2); y3 = gelu1(y3);
  y0 += blo(rr.x); y1 += bhi(rr.x); y2 += blo(rr.y); y3 += bhi(rr.y);
  uint2 pk;
  pk.x = (unsigned int)f2bf(y0) | ((unsigned int)f2bf(y1) << 16);
  pk.y = (unsigned int)f2bf(y2) | ((unsigned int)f2bf(y3) << 16);
  *(uint2*)(xout + (size_t)wv * 128 + c0) = pk;
}

// ---------------- edge aggregation, output layer (padded to 64 ch) ----------------
__global__ __launch_bounds__(256) void edge_out_kernel(
    const unsigned short* __restrict__ xl, const unsigned short* __restrict__ xr,
    const unsigned short* __restrict__ att, const unsigned short* __restrict__ bias,
    void* __restrict__ out, const int* __restrict__ flagp,
    const int* __restrict__ offs, const int* __restrict__ srcs) {
  int wv = blockIdx.x * 4 + (threadIdx.x >> 6);
  if (wv >= NN) return;
  int lane = threadIdx.x & 63;
  int oct = lane >> 3;
  int cb = (lane & 7) * 16;  // byte offset of 8 ch (8 lanes x 16B = 128B row)
  int beg = __builtin_amdgcn_readfirstlane(offs[wv]);
  int last = __builtin_amdgcn_readfirstlane(offs[wv + 1]) - 1;
  const char* xlb = (const char*)xl;
  uint4 xr8 = *(const uint4*)((const char*)xr + (size_t)wv * 128 + cb);
  float rx0 = blo(xr8.x), rx1 = bhi(xr8.x), rx2 = blo(xr8.y), rx3 = bhi(xr8.y);
  float rx4 = blo(xr8.z), rx5 = bhi(xr8.z), rx6 = blo(xr8.w), rx7 = bhi(xr8.w);
  uint4 at8 = *(const uint4*)((const char*)att + cb);
  float a0 = blo(at8.x), a1 = bhi(at8.x), a2 = blo(at8.y), a3 = bhi(at8.y);
  float a4 = blo(at8.z), a5 = bhi(at8.z), a6 = blo(at8.w), a7 = bhi(at8.w);
  float acc0 = 0.f, acc1 = 0.f, acc2 = 0.f, acc3 = 0.f;
  float acc4 = 0.f, acc5 = 0.f, acc6 = 0.f, acc7 = 0.f, den = 0.f;
  // pipeline prologue
  int ir = beg + oct;
  int o_cur = srcs[clampe(ir, last)];
  int o_nxt = srcs[clampe(ir + 8, last)];
  uint4 u = *(const uint4*)(xlb + ((o_cur >> 1) + cb));  // 64-ch rows = 128 B
  for (int e = beg; e <= last; e += 8) {
    int o_p = srcs[clampe(ir + 16, last)];
    uint4 un = *(const uint4*)(xlb + ((o_nxt >> 1) + cb));
    float mk = (ir <= last) ? 1.f : 0.f;
    ir += 8;
    float x0 = blo(u.x), x1 = bhi(u.x), x2 = blo(u.y), x3 = bhi(u.y);
    float x4 = blo(u.z), x5 = bhi(u.z), x6 = blo(u.w), x7 = bhi(u.w);
    float t0 = x0 + rx0, t1 = x1 + rx1, t2 = x2 + rx2, t3 = x3 + rx3;
    float t4 = x4 + rx4, t5 = x5 + rx5, t6 = x6 + rx6, t7 = x7 + rx7;
    float pa = a0 * t0;
    pa = fmaf(a1, t1, pa); pa = fmaf(a2, t2, pa); pa = fmaf(a3, t3, pa);
    pa = fmaf(a4, t4, pa); pa = fmaf(a5, t5, pa); pa = fmaf(a6, t6, pa); pa = fmaf(a7, t7, pa);
    float pb = a0 * fabsf(t0);
    pb = fmaf(a1, fabsf(t1), pb); pb = fmaf(a2, fabsf(t2), pb); pb = fmaf(a3, fabsf(t3), pb);
    pb = fmaf(a4, fabsf(t4), pb); pb = fmaf(a5, fabsf(t5), pb);
    pb = fmaf(a6, fabsf(t6), pb); pb = fmaf(a7, fabsf(t7), pb);
    float p = fmaf(0.4f, pb, 0.6f * pa);
    p = dpp_add<0xB1>(p);   // xor1
    p = dpp_add<0x4E>(p);   // xor2
    p = dpp_add<0x141>(p);  // row_half_mirror -> 8-lane sum = 64-ch dot
    float w = __expf(fminf(p, 60.f)) * mk;
    den += w;
    acc0 = fmaf(w, x0, acc0); acc1 = fmaf(w, x1, acc1);
    acc2 = fmaf(w, x2, acc2); acc3 = fmaf(w, x3, acc3);
    acc4 = fmaf(w, x4, acc4); acc5 = fmaf(w, x5, acc5);
    acc6 = fmaf(w, x6, acc6); acc7 = fmaf(w, x7, acc7);
    u = un;
    o_nxt = o_p;
  }
  // merge the eight octets
  den += __shfl_xor(den, 8);  den += __shfl_xor(den, 16);  den += __shfl_xor(den, 32);
  acc0 += __shfl_xor(acc0, 8); acc0 += __shfl_xor(acc0, 16); acc0 += __shfl_xor(acc0, 32);
  acc1 += __shfl_xor(acc1, 8); acc1 += __shfl_xor(acc1, 16); acc1 += __shfl_xor(acc1, 32);
  acc2 += __shfl_xor(acc2, 8); acc2 += __shfl_xor(acc2, 16); acc2 += __shfl_xor(acc2, 32);
  acc3 += __shfl_xor(acc3, 8); acc3 += __shfl_xor(acc3, 16); acc3 += __shfl_xor(acc3, 32);
  acc4 += __shfl_xor(acc4, 8); acc4 += __shfl_xor(acc4, 16); acc4 += __shfl_xor(acc4, 32);
  acc5 += __shfl_xor(acc5, 8); acc5 += __shfl_xor(acc5, 16); acc5 += __shfl_xor(acc5, 32);
  acc6 += __shfl_xor(acc6, 8); acc6 += __shfl_xor(acc6, 16); acc6 += __shfl_xor(acc6, 32);
  acc7 += __shfl_xor(acc7, 8); acc7 += __shfl_xor(acc7, 16); acc7 += __shfl_xor(acc7, 32);
  float inv = __builtin_amdgcn_rcpf(den + 1e-16f);
  if (lane < 5) {  // lanes 0..4 cover channels 0..39
    uint4 bb = *(const uint4*)((const char*)bias + cb);
    float v0 = acc0 * inv + blo(bb.x), v1 = acc1 * inv + bhi(bb.x);
    float v2 = acc2 * inv + blo(bb.y), v3 = acc3 * inv + bhi(bb.y);
    float v4 = acc4 * inv + blo(bb.z), v5 = acc5 * inv + bhi(bb.z);
    float v6 = acc6 * inv + blo(bb.w), v7 = acc7 * inv + bhi(bb.w);
    int c0 = lane * 8;
    if (*flagp) {
      float* op = (float*)out + (size_t)wv * OUTD + c0;
      float4 f0 = {v0, v1, v2, v3};
      float4 f1 = {v4, v5, v6, v7};
      *(float4*)(op) = f0;
      *(float4*)(op + 4) = f1;
    } else {
      uint4 pk;
      pk.x = (unsigned int)f2bf(v0) | ((unsigned int)f2bf(v1) << 16);
      pk.y = (unsigned int)f2bf(v2) | ((unsigned int)f2bf(v3) << 16);
      pk.z = (unsigned int)f2bf(v4) | ((unsigned int)f2bf(v5) << 16);
      pk.w = (unsigned int)f2bf(v6) | ((unsigned int)f2bf(v7) << 16);
      *(uint4*)((unsigned short*)out + (size_t)wv * OUTD + c0) = pk;
    }
  }
}

extern "C" void kernel_launch(void* const* d_in, const int* in_sizes, int n_in,
                              void* d_out, int out_size, void* d_ws, size_t ws_size,
                              hipStream_t stream) {
  const void* x = d_in[0];
  const void* ei = d_in[1];

  char* ws = (char*)d_ws;
  size_t o = 0;
  auto alloc = [&](size_t bytes) {
    void* p = ws + o;
    o = (o + bytes + 255) & ~(size_t)255;
    return p;
  };
  int* flags = (int*)alloc(256);
  int* src_sorted = (int*)alloc((size_t)EE * 4);
  int* offs = (int*)alloc((size_t)(NN + 1) * 4);
  int* bcur = (int*)alloc((size_t)NBUCK * 16 * 4);
  unsigned int* bedges = (unsigned int*)alloc((size_t)NBUCK * BCAP * 4);
  unsigned short* F_W0 = (unsigned short*)alloc(2048 * 16);
  unsigned short* F_W1l = (unsigned short*)alloc(2048 * 16);
  unsigned short* F_W1r = (unsigned short*)alloc(2048 * 16);
  unsigned short* F_W2l = (unsigned short*)alloc(2048 * 16);
  unsigned short* F_W2r = (unsigned short*)alloc(2048 * 16);
  unsigned short* F_W3l = (unsigned short*)alloc(1024 * 16);
  unsigned short* F_W3r = (unsigned short*)alloc(1024 * 16);
  unsigned short* pblk = (unsigned short*)alloc(4096);
  unsigned short* ident = (unsigned short*)alloc((size_t)NN * 128 * 2);  // x1, then x2
  unsigned short* bxl = (unsigned short*)alloc((size_t)NN * 128 * 2);
  unsigned short* bxr = (unsigned short*)alloc((size_t)NN * 128 * 2);
  unsigned short* xbf = (unsigned short*)alloc((size_t)NN * 128 * 2);  // bf16 A cache
  (void)ws_size;

  unsigned short* pb0 = pblk;
  unsigned short* pb1l = pblk + 128;
  unsigned short* pb1r = pblk + 256;
  unsigned short* patt1 = pblk + 384;
  unsigned short* pbias1 = pblk + 512;
  unsigned short* pg1 = pblk + 640;
  unsigned short* pbe1 = pblk + 768;
  unsigned short* pb2l = pblk + 896;
  unsigned short* pb2r = pblk + 1024;
  unsigned short* patt2 = pblk + 1152;
  unsigned short* pbias2 = pblk + 1280;
  unsigned short* pg2 = pblk + 1408;
  unsigned short* pbe2 = pblk + 1536;
  unsigned short* pb3l = pblk + 1664;   // cap 64 (zero-padded)
  unsigned short* pb3r = pblk + 1728;   // cap 64
  unsigned short* patt3 = pblk + 1792;  // cap 64
  unsigned short* pbias3 = pblk + 1856; // cap 64

  // ---- init: weights + params + flags + bucket cursors ----
  WDescs wd;
  wd.d[0] = {d_in[2], F_W0, 8, 128};
  wd.d[1] = {d_in[4], F_W1l, 8, 128};
  wd.d[2] = {d_in[6], F_W1r, 8, 128};
  wd.d[3] = {d_in[12], F_W2l, 8, 128};
  wd.d[4] = {d_in[14], F_W2r, 8, 128};
  wd.d[5] = {d_in[20], F_W3l, 4, 40};  // T=4 -> 64 padded cols
  wd.d[6] = {d_in[22], F_W3r, 4, 40};
  int cum[8] = {0, 2048, 4096, 6144, 8192, 10240, 11264, 12288};
  for (int i = 0; i < 8; ++i) wd.cum[i] = cum[i];
  PCvs P;
  P.a[0] = {d_in[3], pb0, 128, 128};
  P.a[1] = {d_in[5], pb1l, 128, 128};
  P.a[2] = {d_in[7], pb1r, 128, 128};
  P.a[3] = {d_in[8], patt1, 128, 128};
  P.a[4] = {d_in[9], pbias1, 128, 128};
  P.a[5] = {d_in[10], pg1, 128, 128};
  P.a[6] = {d_in[11], pbe1, 128, 128};
  P.a[7] = {d_in[13], pb2l, 128, 128};
  P.a[8] = {d_in[15], pb2r, 128, 128};
  P.a[9] = {d_in[16], patt2, 128, 128};
  P.a[10] = {d_in[17], pbias2, 128, 128};
  P.a[11] = {d_in[18], pg2, 128, 128};
  P.a[12] = {d_in[19], pbe2, 128, 128};
  P.a[13] = {d_in[21], pb3l, 40, 64};
  P.a[14] = {d_in[23], pb3r, 40, 64};
  P.a[15] = {d_in[24], patt3, 40, 64};
  P.a[16] = {d_in[25], pbias3, 40, 64};
  init_kernel<<<66, 256, 0, stream>>>(ei, x, flags, bcur, wd, P);

  const int* fx = flags + 1;
  const int* f0 = flags + 2;
  const int gb8 = (NN + 127) / 128;   // 391 blocks, 8 waves each, 16 rows/wave
  const int gb4 = (NN / 16 + 3) / 4;  // 782 blocks, 4 waves each
  const int eb = (NN + 3) / 4;        // 12500 blocks, 1 wave/dst (edge_out)
  const int eb2 = (NN / 2 + 3) / 4;   // 6250 blocks, 2 dsts/wave (edge_hid)

  // ---- fused pass 1: edge bucket scatter || identity GEMM (W0 -> ident, + xbf) ----
  GArgs gi; gi.s[0] = {F_W0, pb0, ident};
  gi.s[1] = {nullptr, nullptr, nullptr}; gi.s[2] = {nullptr, nullptr, nullptr};
  fused_scatter_gemm<<<ABLKS + gb8, 512, 0, stream>>>(ei, bedges, bcur, x, fx, gi, 1,
                                                      NN, 8, 128, xbf);

  // ---- fused pass 2: per-bucket sort || layer-1 l/r GEMM (W1l,W1r -> bxl,bxr) ----
  GArgs g1a; g1a.s[0] = {F_W1l, pb1l, bxl}; g1a.s[1] = {F_W1r, pb1r, bxr};
  g1a.s[2] = {nullptr, nullptr, nullptr};
  fused_sort_gemm<<<NBUCK + gb8, 512, 0, stream>>>(bedges, bcur, offs, src_sorted, x,
                                                   fx, g1a, 2, NN, 8, 128, xbf);

  // ---- layer 1 aggregation ----
  edge_hid_kernel<<<eb2, 256, 0, stream>>>(bxl, bxr, patt1, pbias1, pg1, pbe1, ident,
                                           ident, offs, src_sorted);

  // ---- layer 2 ----
  GArgs g2a; g2a.s[0] = {F_W2l, pb2l, bxl}; g2a.s[1] = {F_W2r, pb2r, bxr};
  g2a.s[2] = {nullptr, nullptr, nullptr};
  gemm_multi_kernel<<<gb4, 256, 0, stream>>>(ident, f0, g2a, 2, NN, 8, 128);
  edge_hid_kernel<<<eb2, 256, 0, stream>>>(bxl, bxr, patt2, pbias2, pg2, pbe2, ident,
                                           ident, offs, src_sorted);

  // ---- layer 3 (padded 64 ch) ----
  GArgs g3a; g3a.s[0] = {F_W3l, pb3l, bxl}; g3a.s[1] = {F_W3r, pb3r, bxr};
  g3a.s[2] = {nullptr, nullptr, nullptr};
  gemm_multi_kernel<<<gb4, 256, 0, stream>>>(ident, f0, g3a, 2, NN, 4, 64);
  edge_out_kernel<<<eb, 256, 0, stream>>>(bxl, bxr, patt3, pbias3, d_out, fx, offs,
                                          src_sorted);
}

// Round 4
// 306.561 us; speedup vs baseline: 1.0515x; 1.0515x over previous
//
#include <hip/hip_runtime.h>
#include <hip/hip_bf16.h>

#define NN 50000
#define EE 800000
#define OUTD 40
#define NBUCK 196   // dst >> 8 buckets (50000/256 -> 0..195)
#define BCAP 8192   // slots per bucket (avg fill ~4082)
#define ABLKS 400   // scatter blocks (>= 1.5 per CU)
#define EPB 2000    // edges per scatter block

typedef __attribute__((ext_vector_type(8))) short short8;
typedef __attribute__((ext_vector_type(4))) float floatx4;

__device__ __forceinline__ float bf2f(unsigned short u) {
  union { unsigned int i; float f; } v; v.i = ((unsigned int)u) << 16; return v.f;
}
__device__ __forceinline__ unsigned short f2bf(float f) {
  union { float f; unsigned int i; } v; v.f = f;
  unsigned int x = v.i;
  return (unsigned short)((x + 0x7fffu + ((x >> 16) & 1u)) >> 16);  // RNE, finite-only
}
__device__ __forceinline__ float blo(unsigned int u) {
  union { unsigned int i; float f; } v; v.i = u << 16; return v.f;
}
__device__ __forceinline__ float bhi(unsigned int u) {
  union { unsigned int i; float f; } v; v.i = u & 0xffff0000u; return v.f;
}

template <int CTRL>
__device__ __forceinline__ float dpp_add(float x) {
  int y = __builtin_amdgcn_update_dpp(0, __float_as_int(x), CTRL, 0xF, 0xF, true);
  return x + __int_as_float(y);
}

// tanh-approx GELU (max abs err ~1e-3, well inside bf16 tolerance)
__device__ __forceinline__ float gelu1(float y) {
  float y2 = y * y;
  float z = y * fmaf(0.0356774081f, y2, 0.7978845608f);
  float e = __expf(-2.f * z);
  float r = __builtin_amdgcn_rcpf(1.f + e);
  float th = fmaf(2.f, r, -1.f);
  return y * fmaf(0.5f, th, 0.5f);
}

// clamp edge index into [0, last]
__device__ __forceinline__ int clampe(int i, int last) {
  int r = i <= last ? i : last;
  return r < 0 ? 0 : r;
}

// wave-local dtype probes (same 512B window everywhere -> identical result)
__device__ __forceinline__ int probe_f32(const void* x) {
  int lane = threadIdx.x & 63;
  unsigned short u = ((const unsigned short*)x)[2 * lane];
  int exf = (u >> 7) & 0xFF;
  unsigned long long b = __ballot((exf >= 100 && exf <= 142) ? 1 : 0);
  return (__popcll(b) >= 48) ? 0 : 1;
}
__device__ __forceinline__ int probe_i64(const void* ei) {
  int lane = threadIdx.x & 63;
  long long v = ((const long long*)ei)[lane];
  unsigned long long b = __ballot((v >= 0 && v < NN) ? 1 : 0);
  return (__popcll(b) >= 48) ? 1 : 0;
}

// ---------------- weight rearrange + param convert descriptors ----------------
struct WDesc { const void* W; unsigned short* F; int T; int ncols; };
struct WDescs { WDesc d[7]; int cum[8]; };
struct PCv { const void* s; unsigned short* d; int n; int cap; };
struct PCvs { PCv a[17]; };

// ---------------- init: weights + params + flags + bucket-cursor zero ----------------
__global__ __launch_bounds__(256) void init_kernel(const void* __restrict__ ei,
                                                   const void* __restrict__ x,
                                                   int* __restrict__ flags,
                                                   int* __restrict__ bcur,
                                                   WDescs ds, PCvs P) {
  int b = blockIdx.x;
  int f32 = probe_f32(x);
  if (b < 48) {
    int idx = b * 256 + threadIdx.x;
    if (idx >= 12288) return;
    int mi = 0;
    while (idx >= ds.cum[mi + 1]) mi++;
    int local = idx - ds.cum[mi];
    WDesc d = ds.d[mi];
    int lane = local & 63;
    int rest = local >> 6;
    int t = rest % d.T;
    int kb = rest / d.T;
    int m = lane & 15, quad = lane >> 4;
    int col = t * 16 + m;
    short8 v;
    for (int j = 0; j < 8; ++j) {
      int k = kb * 32 + quad * 8 + j;
      if (col < d.ncols) {
        int off = k * d.ncols + col;
        v[j] = f32 ? (short)f2bf(((const float*)d.W)[off])
                   : (short)((const unsigned short*)d.W)[off];
      } else {
        v[j] = 0;
      }
    }
    *(short8*)(d.F + (size_t)local * 8) = v;
  } else if (b < 65) {
    PCv p = P.a[b - 48];
    for (int i = threadIdx.x; i < p.cap; i += 256) {
      unsigned short o = 0;
      if (i < p.n)
        o = f32 ? f2bf(((const float*)p.s)[i]) : ((const unsigned short*)p.s)[i];
      p.d[i] = o;
    }
  } else {
    for (int i = threadIdx.x; i < NBUCK * 16; i += 256) bcur[i] = 0;
    if (threadIdx.x < 64) {
      int i64 = probe_i64(ei);
      if (threadIdx.x == 0) {
        flags[0] = i64;
        flags[1] = f32;
        flags[2] = 0;
      }
    }
  }
}

// ---------------- multi-output GEMM body: Out_i[M,ncols] = A[M,128] @ W_i + b_i ----
struct GSet { const unsigned short* F; const unsigned short* bias; unsigned short* Out; };
struct GArgs { GSet s[3]; };

__device__ __forceinline__ short8 pack_f4(float4 u0, float4 u1) {
  short8 r;
  r[0] = (short)f2bf(u0.x); r[1] = (short)f2bf(u0.y);
  r[2] = (short)f2bf(u0.z); r[3] = (short)f2bf(u0.w);
  r[4] = (short)f2bf(u1.x); r[5] = (short)f2bf(u1.y);
  r[6] = (short)f2bf(u1.z); r[7] = (short)f2bf(u1.w);
  return r;
}

__device__ __forceinline__ void gemm_body(int wave, int lane, const void* __restrict__ A,
                                          int f32, const GArgs& g, int nset, int M,
                                          int T, int ncols) {
  int r0 = wave * 16;
  if (r0 >= M) return;
  int m = lane & 15, quad = lane >> 4;
  short8 a0, a1, a2, a3;
  if (!f32) {
    const unsigned short* ar = (const unsigned short*)A + (size_t)(r0 + m) * 128 + quad * 8;
    a0 = *(const short8*)(ar);
    a1 = *(const short8*)(ar + 32);
    a2 = *(const short8*)(ar + 64);
    a3 = *(const short8*)(ar + 96);
  } else {
    const float* ar = (const float*)A + (size_t)(r0 + m) * 128 + quad * 8;
    a0 = pack_f4(*(const float4*)(ar), *(const float4*)(ar + 4));
    a1 = pack_f4(*(const float4*)(ar + 32), *(const float4*)(ar + 36));
    a2 = pack_f4(*(const float4*)(ar + 64), *(const float4*)(ar + 68));
    a3 = pack_f4(*(const float4*)(ar + 96), *(const float4*)(ar + 100));
  }
  size_t kstride = (size_t)T * 64 * 8;
  for (int si = 0; si < nset; ++si) {
    const unsigned short* F = g.s[si].F;
    const unsigned short* bias = g.s[si].bias;
    unsigned short* Out = g.s[si].Out;
    for (int t = 0; t < T; ++t) {
      floatx4 acc = {0.f, 0.f, 0.f, 0.f};
      const unsigned short* wp = F + ((size_t)t * 64 + lane) * 8;
      acc = __builtin_amdgcn_mfma_f32_16x16x32_bf16(a0, *(const short8*)(wp), acc, 0, 0, 0);
      acc = __builtin_amdgcn_mfma_f32_16x16x32_bf16(a1, *(const short8*)(wp + kstride), acc, 0, 0, 0);
      acc = __builtin_amdgcn_mfma_f32_16x16x32_bf16(a2, *(const short8*)(wp + 2 * kstride), acc, 0, 0, 0);
      acc = __builtin_amdgcn_mfma_f32_16x16x32_bf16(a3, *(const short8*)(wp + 3 * kstride), acc, 0, 0, 0);
      int col = t * 16 + m;
      if (col < ncols) {
        float bb = bf2f(bias[col]);
        for (int r = 0; r < 4; ++r) {
          int row = r0 + quad * 4 + r;
          Out[(size_t)row * ncols + col] = f2bf(acc[r] + bb);
        }
      }
    }
  }
}

// ---------------- fused: scatter (blocks < ABLKS) || layer-1 identity GEMM ----------
__global__ __launch_bounds__(512) void fused_scatter_gemm(
    const void* __restrict__ ei, unsigned int* __restrict__ bedges,
    int* __restrict__ bcur, const void* __restrict__ A,
    const int* __restrict__ flagp, GArgs g, int nset, int M, int T, int ncols) {
  __shared__ int lhist[NBUCK];
  __shared__ int lbase[NBUCK];
  if (blockIdx.x >= ABLKS) {
    int wave = (blockIdx.x - ABLKS) * 8 + (threadIdx.x >> 6);
    gemm_body(wave, threadIdx.x & 63, A, *flagp, g, nset, M, T, ncols);
    return;
  }
  int tid = threadIdx.x;
  if (tid < NBUCK) lhist[tid] = 0;
  int i64 = probe_i64(ei);
  __syncthreads();
  int e0 = blockIdx.x * EPB;
  int e1 = e0 + EPB; if (e1 > EE) e1 = EE;
  // phase 1: local histogram of dst bins
  for (int e = e0 + tid; e < e1; e += 512) {
    int d = i64 ? (int)((const long long*)ei)[EE + e] : ((const int*)ei)[EE + e];
    d = d < 0 ? 0 : (d >= NN ? NN - 1 : d);
    atomicAdd(&lhist[d >> 8], 1);
  }
  __syncthreads();
  // phase 2: one global reservation per bin
  if (tid < NBUCK) {
    int c = lhist[tid];
    lbase[tid] = c ? atomicAdd(&bcur[tid * 16], c) : 0;  // cursors padded to 64B
    lhist[tid] = 0;                                      // reuse as local cursor
  }
  __syncthreads();
  // phase 3: ranked scatter
  for (int e = e0 + tid; e < e1; e += 512) {
    int s, d;
    if (i64) {
      s = (int)((const long long*)ei)[e];
      d = (int)((const long long*)ei)[EE + e];
    } else {
      s = ((const int*)ei)[e];
      d = ((const int*)ei)[EE + e];
    }
    s = s < 0 ? 0 : (s >= NN ? NN - 1 : s);
    d = d < 0 ? 0 : (d >= NN ? NN - 1 : d);
    int bin = d >> 8;
    int r = atomicAdd(&lhist[bin], 1);
    int pos = lbase[bin] + r;
    if (pos < BCAP)
      bedges[(size_t)bin * BCAP + pos] =
          ((unsigned int)(d & 0xFF) << 24) | ((unsigned int)s << 8);
  }
}

// ---------------- fused: per-bucket dst sort (blocks < NBUCK) || layer-1 l/r GEMM ----
__global__ __launch_bounds__(512) void fused_sort_gemm(
    const unsigned int* __restrict__ bedges, const int* __restrict__ bcur,
    int* __restrict__ offs, int* __restrict__ src_sorted,
    const void* __restrict__ A, const int* __restrict__ flagp, GArgs g,
    int nset, int M, int T, int ncols) {
  __shared__ int lhist[256];
  __shared__ int lscan[256];
  __shared__ int lbin[256];
  __shared__ int sbase, scount, stotal;
  __shared__ unsigned int le[BCAP];
  __shared__ unsigned short lrank[BCAP];
  if (blockIdx.x >= NBUCK) {
    int wave = (blockIdx.x - NBUCK) * 8 + (threadIdx.x >> 6);
    gemm_body(wave, threadIdx.x & 63, A, *flagp, g, nset, M, T, ncols);
    return;
  }
  int k = blockIdx.x;
  int tid = threadIdx.x;
  if (tid < 256) {
    int c = 0;
    if (tid < NBUCK) {
      int v = bcur[tid * 16];
      c = v < BCAP ? v : BCAP;
    }
    lscan[tid] = c;
  }
  __syncthreads();
  for (int off = 1; off < 256; off <<= 1) {
    int u = 0;
    if (tid < 256 && tid >= off) u = lscan[tid - off];
    __syncthreads();
    if (tid < 256) lscan[tid] += u;
    __syncthreads();
  }
  if (tid == 0) {
    int pb = (k == 0) ? 0 : lscan[k - 1];
    sbase = pb;
    scount = lscan[k] - pb;
    stotal = lscan[NBUCK - 1];
  }
  if (tid < 256) lhist[tid] = 0;
  __syncthreads();
  int base = sbase, count = scount;
  const unsigned int* myb = bedges + (size_t)k * BCAP;
  for (int i = tid; i < count; i += 512) {
    unsigned int pk = myb[i];
    int bin = pk >> 24;
    int r = atomicAdd(&lhist[bin], 1);
    le[i] = pk;
    lrank[i] = (unsigned short)r;
  }
  __syncthreads();
  int hc = 0;
  if (tid < 256) {
    hc = lhist[tid];
    lscan[tid] = hc;
  }
  __syncthreads();
  for (int off = 1; off < 256; off <<= 1) {
    int u = 0;
    if (tid < 256 && tid >= off) u = lscan[tid - off];
    __syncthreads();
    if (tid < 256) lscan[tid] += u;
    __syncthreads();
  }
  if (tid < 256) {
    int binoff = lscan[tid] - hc;  // exclusive within bucket
    lbin[tid] = binoff;
    int node = k * 256 + tid;
    if (node < NN) offs[node] = base + binoff;
    if (k == 0 && tid == 0) offs[NN] = stotal;
  }
  __syncthreads();
  for (int i = tid; i < count; i += 512) {
    unsigned int pk = le[i];
    int bin = pk >> 24;
    int pos = base + lbin[bin] + (int)lrank[i];
    src_sorted[pos] = (int)(pk & 0x00FFFF00u);  // src<<8 byte offset
  }
}

// ---------------- edge aggregation, hidden layers (H=4, C=32) ----------------
// Main loop at the compulsory cross-XCD L2-fill roofline (~90 MB @ ~2.3 TB/s).
// FUSED EPILOGUE: the block's 8 finished x-rows are staged to LDS (bf16) and
// the next layer's row-local GEMM (x_row @ Wl/Wr) runs right here on the idle
// MFMA pipe — eliminates the standalone gemm2/gemm3 dispatches entirely.
// TT = weight tiles (8 -> 128 cols, 4 -> 64 cols); WRITEX: materialize x row.
template <int TT, int NCOLS, int WRITEX>
__global__ __launch_bounds__(256) void edge_hid_kernel(
    const unsigned short* __restrict__ xl, const unsigned short* __restrict__ xr,
    const unsigned short* __restrict__ att, const unsigned short* __restrict__ bias,
    const unsigned short* __restrict__ gamma, const unsigned short* __restrict__ beta,
    const unsigned short* __restrict__ resid, unsigned short* __restrict__ xout,
    const int* __restrict__ offs, const int* __restrict__ srcs,
    const unsigned short* __restrict__ Fl, const unsigned short* __restrict__ Fr,
    const unsigned short* __restrict__ bl, const unsigned short* __restrict__ br,
    unsigned short* __restrict__ outl, unsigned short* __restrict__ outr) {
  __shared__ unsigned short sA[16 * 128];  // 8 real rows + 8 zero rows
  int wpair = blockIdx.x * 4 + (threadIdx.x >> 6);
  int lane = threadIdx.x & 63;
  int half = lane >> 5;
  int wv = wpair * 2 + half;
  // NN is a multiple of 8 and grid covers it exactly -> no early returns,
  // so the epilogue __syncthreads below is safe.
  int hl = lane & 31;
  int sub = hl >> 4;          // edge slot (0/1) within this half
  int cb = (hl & 15) * 16;    // byte offset of this lane's 8 channels (256 B/row)
  int beg = offs[wv], end = offs[wv + 1], last = end - 1;
  int iters = (end - beg + 1) >> 1;  // ceil(deg/2)
  int oi = __shfl_xor(iters, 32);
  int maxit = __builtin_amdgcn_readfirstlane(iters > oi ? iters : oi);
  const char* xlb = (const char*)xl;
  int c0 = hl * 4;
  // hoisted epilogue load: resid row latency hides under the whole edge loop
  uint2 rr = *(const uint2*)(resid + (size_t)wv * 128 + c0);
  uint4 xr8 = *(const uint4*)((const char*)xr + (size_t)wv * 256 + cb);
  float rx0 = blo(xr8.x), rx1 = bhi(xr8.x), rx2 = blo(xr8.y), rx3 = bhi(xr8.y);
  float rx4 = blo(xr8.z), rx5 = bhi(xr8.z), rx6 = blo(xr8.w), rx7 = bhi(xr8.w);
  uint4 at8 = *(const uint4*)((const char*)att + cb);
  float a0 = blo(at8.x), a1 = bhi(at8.x), a2 = blo(at8.y), a3 = bhi(at8.y);
  float a4 = blo(at8.z), a5 = bhi(at8.z), a6 = blo(at8.w), a7 = bhi(at8.w);
  float acc0 = 0.f, acc1 = 0.f, acc2 = 0.f, acc3 = 0.f;
  float acc4 = 0.f, acc5 = 0.f, acc6 = 0.f, acc7 = 0.f, den = 0.f;
  // pipeline prologue: index for edge 0 and edge 1, gather for edge 0
  int ir = beg + sub;
  int o_cur = srcs[clampe(ir, last)];
  int o_nxt = srcs[clampe(ir + 2, last)];
  uint4 u = *(const uint4*)(xlb + (o_cur + cb));
  for (int it = 0; it < maxit; ++it) {
    int o_p = srcs[clampe(ir + 4, last)];
    uint4 un = *(const uint4*)(xlb + (o_nxt + cb));
    float mk = (ir <= last) ? 1.f : 0.f;
    ir += 2;
    float x0 = blo(u.x), x1 = bhi(u.x), x2 = blo(u.y), x3 = bhi(u.y);
    float x4 = blo(u.z), x5 = bhi(u.z), x6 = blo(u.w), x7 = bhi(u.w);
    float t0 = x0 + rx0, t1 = x1 + rx1, t2 = x2 + rx2, t3 = x3 + rx3;
    float t4 = x4 + rx4, t5 = x5 + rx5, t6 = x6 + rx6, t7 = x7 + rx7;
    float pa = a0 * t0;
    pa = fmaf(a1, t1, pa); pa = fmaf(a2, t2, pa); pa = fmaf(a3, t3, pa);
    pa = fmaf(a4, t4, pa); pa = fmaf(a5, t5, pa); pa = fmaf(a6, t6, pa); pa = fmaf(a7, t7, pa);
    float pb = a0 * fabsf(t0);
    pb = fmaf(a1, fabsf(t1), pb); pb = fmaf(a2, fabsf(t2), pb); pb = fmaf(a3, fabsf(t3), pb);
    pb = fmaf(a4, fabsf(t4), pb); pb = fmaf(a5, fabsf(t5), pb);
    pb = fmaf(a6, fabsf(t6), pb); pb = fmaf(a7, fabsf(t7), pb);
    float p = fmaf(0.4f, pb, 0.6f * pa);
    p = dpp_add<0xB1>(p);  // quad xor1
    p = dpp_add<0x4E>(p);  // quad xor2 -> 4-lane head sum (32 ch)
    float w = __expf(fminf(p, 60.f)) * mk;
    den += w;
    acc0 = fmaf(w, x0, acc0); acc1 = fmaf(w, x1, acc1);
    acc2 = fmaf(w, x2, acc2); acc3 = fmaf(w, x3, acc3);
    acc4 = fmaf(w, x4, acc4); acc5 = fmaf(w, x5, acc5);
    acc6 = fmaf(w, x6, acc6); acc7 = fmaf(w, x7, acc7);
    u = un;
    o_nxt = o_p;
  }
  // merge the two edge slots within each half (xor16 stays inside the half)
  den += __shfl_xor(den, 16);
  acc0 += __shfl_xor(acc0, 16); acc1 += __shfl_xor(acc1, 16);
  acc2 += __shfl_xor(acc2, 16); acc3 += __shfl_xor(acc3, 16);
  acc4 += __shfl_xor(acc4, 16); acc5 += __shfl_xor(acc5, 16);
  acc6 += __shfl_xor(acc6, 16); acc7 += __shfl_xor(acc7, 16);
  // redistribute to 4 ch/lane within each half (32 lanes per dst)
  int srcLane = (half << 5) + (hl >> 1);
  float b0 = __shfl(acc0, srcLane), b1 = __shfl(acc1, srcLane);
  float b2 = __shfl(acc2, srcLane), b3 = __shfl(acc3, srcLane);
  float h4 = __shfl(acc4, srcLane), h5 = __shfl(acc5, srcLane);
  float h6 = __shfl(acc6, srcLane), h7 = __shfl(acc7, srcLane);
  float dn = __shfl(den, srcLane);
  bool hi = (hl & 1) != 0;
  float v0 = hi ? h4 : b0, v1 = hi ? h5 : b1, v2 = hi ? h6 : b2, v3 = hi ? h7 : b3;
  float inv = __builtin_amdgcn_rcpf(dn + 1e-16f);
  uint2 bb = *(const uint2*)(bias + c0);
  float o0 = v0 * inv + blo(bb.x), o1 = v1 * inv + bhi(bb.x);
  float o2 = v2 * inv + blo(bb.y), o3 = v3 * inv + bhi(bb.y);
  // LayerNorm over 128 ch: 32-lane reduction within each half
  float s = (o0 + o1) + (o2 + o3);
  for (int k = 1; k < 32; k <<= 1) s += __shfl_xor(s, k);
  float mu = s * (1.f / 128.f);
  float d0 = o0 - mu, d1 = o1 - mu, d2 = o2 - mu, d3 = o3 - mu;
  float q = (d0 * d0 + d1 * d1) + (d2 * d2 + d3 * d3);
  for (int k = 1; k < 32; k <<= 1) q += __shfl_xor(q, k);
  float rstd = rsqrtf(q * (1.f / 128.f) + 1e-5f);
  uint2 gg = *(const uint2*)(gamma + c0);
  uint2 be = *(const uint2*)(beta + c0);
  float y0 = d0 * rstd * blo(gg.x) + blo(be.x);
  float y1 = d1 * rstd * bhi(gg.x) + bhi(be.x);
  float y2 = d2 * rstd * blo(gg.y) + blo(be.y);
  float y3 = d3 * rstd * bhi(gg.y) + bhi(be.y);
  y0 = gelu1(y0); y1 = gelu1(y1); y2 = gelu1(y2); y3 = gelu1(y3);
  y0 += blo(rr.x); y1 += bhi(rr.x); y2 += blo(rr.y); y3 += bhi(rr.y);
  uint2 pk;
  pk.x = (unsigned int)f2bf(y0) | ((unsigned int)f2bf(y1) << 16);
  pk.y = (unsigned int)f2bf(y2) | ((unsigned int)f2bf(y3) << 16);
  if (WRITEX) *(uint2*)(xout + (size_t)wv * 128 + c0) = pk;

  // ---- fused row-local GEMM epilogue: Out{l,r}[row] = x_row @ W{l,r} + b ----
  int lrow = (threadIdx.x >> 6) * 2 + half;                  // 0..7 local row
  *(uint2*)(&sA[lrow * 128 + c0]) = pk;                      // stage bf16 row
  *(uint2*)(&sA[1024 + threadIdx.x * 4]) = make_uint2(0, 0); // zero rows 8..15
  __syncthreads();
  int m = lane & 15, quad = lane >> 4;
  const unsigned short* arow = sA + m * 128 + quad * 8;
  short8 A0 = *(const short8*)(arow);
  short8 A1 = *(const short8*)(arow + 32);
  short8 A2 = *(const short8*)(arow + 64);
  short8 A3 = *(const short8*)(arow + 96);
  const size_t kst = (size_t)TT * 64 * 8;
  const int rowbase = blockIdx.x * 8;
  const int wid = threadIdx.x >> 6;
  constexpr int PER = (2 * TT) / 4;  // tile-columns per wave (l and r mats)
#pragma unroll
  for (int jj = 0; jj < PER; ++jj) {
    int j = wid * PER + jj;
    bool isr = j >= TT;
    const unsigned short* F = isr ? Fr : Fl;
    const unsigned short* bs = isr ? br : bl;
    unsigned short* Out = isr ? outr : outl;
    int t = isr ? j - TT : j;
    floatx4 acc = {0.f, 0.f, 0.f, 0.f};
    const unsigned short* wp = F + ((size_t)t * 64 + lane) * 8;
    acc = __builtin_amdgcn_mfma_f32_16x16x32_bf16(A0, *(const short8*)(wp), acc, 0, 0, 0);
    acc = __builtin_amdgcn_mfma_f32_16x16x32_bf16(A1, *(const short8*)(wp + kst), acc, 0, 0, 0);
    acc = __builtin_amdgcn_mfma_f32_16x16x32_bf16(A2, *(const short8*)(wp + 2 * kst), acc, 0, 0, 0);
    acc = __builtin_amdgcn_mfma_f32_16x16x32_bf16(A3, *(const short8*)(wp + 3 * kst), acc, 0, 0, 0);
    int col = t * 16 + m;
    float bbv = bf2f(bs[col]);
    if (quad < 2) {  // D rows quad*4+r -> only rows 0..7 are real
#pragma unroll
      for (int r = 0; r < 4; ++r)
        Out[(size_t)(rowbase + quad * 4 + r) * NCOLS + col] = f2bf(acc[r] + bbv);
    }
  }
}

// ---------------- edge aggregation, output layer (padded to 64 ch) ----------------
__global__ __launch_bounds__(256) void edge_out_kernel(
    const unsigned short* __restrict__ xl, const unsigned short* __restrict__ xr,
    const unsigned short* __restrict__ att, const unsigned short* __restrict__ bias,
    void* __restrict__ out, const int* __restrict__ flagp,
    const int* __restrict__ offs, const int* __restrict__ srcs) {
  int wv = blockIdx.x * 4 + (threadIdx.x >> 6);
  if (wv >= NN) return;
  int lane = threadIdx.x & 63;
  int oct = lane >> 3;
  int cb = (lane & 7) * 16;  // byte offset of 8 ch (8 lanes x 16B = 128B row)
  int beg = __builtin_amdgcn_readfirstlane(offs[wv]);
  int last = __builtin_amdgcn_readfirstlane(offs[wv + 1]) - 1;
  const char* xlb = (const char*)xl;
  uint4 xr8 = *(const uint4*)((const char*)xr + (size_t)wv * 128 + cb);
  float rx0 = blo(xr8.x), rx1 = bhi(xr8.x), rx2 = blo(xr8.y), rx3 = bhi(xr8.y);
  float rx4 = blo(xr8.z), rx5 = bhi(xr8.z), rx6 = blo(xr8.w), rx7 = bhi(xr8.w);
  uint4 at8 = *(const uint4*)((const char*)att + cb);
  float a0 = blo(at8.x), a1 = bhi(at8.x), a2 = blo(at8.y), a3 = bhi(at8.y);
  float a4 = blo(at8.z), a5 = bhi(at8.z), a6 = blo(at8.w), a7 = bhi(at8.w);
  float acc0 = 0.f, acc1 = 0.f, acc2 = 0.f, acc3 = 0.f;
  float acc4 = 0.f, acc5 = 0.f, acc6 = 0.f, acc7 = 0.f, den = 0.f;
  // pipeline prologue
  int ir = beg + oct;
  int o_cur = srcs[clampe(ir, last)];
  int o_nxt = srcs[clampe(ir + 8, last)];
  uint4 u = *(const uint4*)(xlb + ((o_cur >> 1) + cb));  // 64-ch rows = 128 B
  for (int e = beg; e <= last; e += 8) {
    int o_p = srcs[clampe(ir + 16, last)];
    uint4 un = *(const uint4*)(xlb + ((o_nxt >> 1) + cb));
    float mk = (ir <= last) ? 1.f : 0.f;
    ir += 8;
    float x0 = blo(u.x), x1 = bhi(u.x), x2 = blo(u.y), x3 = bhi(u.y);
    float x4 = blo(u.z), x5 = bhi(u.z), x6 = blo(u.w), x7 = bhi(u.w);
    float t0 = x0 + rx0, t1 = x1 + rx1, t2 = x2 + rx2, t3 = x3 + rx3;
    float t4 = x4 + rx4, t5 = x5 + rx5, t6 = x6 + rx6, t7 = x7 + rx7;
    float pa = a0 * t0;
    pa = fmaf(a1, t1, pa); pa = fmaf(a2, t2, pa); pa = fmaf(a3, t3, pa);
    pa = fmaf(a4, t4, pa); pa = fmaf(a5, t5, pa); pa = fmaf(a6, t6, pa); pa = fmaf(a7, t7, pa);
    float pb = a0 * fabsf(t0);
    pb = fmaf(a1, fabsf(t1), pb); pb = fmaf(a2, fabsf(t2), pb); pb = fmaf(a3, fabsf(t3), pb);
    pb = fmaf(a4, fabsf(t4), pb); pb = fmaf(a5, fabsf(t5), pb);
    pb = fmaf(a6, fabsf(t6), pb); pb = fmaf(a7, fabsf(t7), pb);
    float p = fmaf(0.4f, pb, 0.6f * pa);
    p = dpp_add<0xB1>(p);   // xor1
    p = dpp_add<0x4E>(p);   // xor2
    p = dpp_add<0x141>(p);  // row_half_mirror -> 8-lane sum = 64-ch dot
    float w = __expf(fminf(p, 60.f)) * mk;
    den += w;
    acc0 = fmaf(w, x0, acc0); acc1 = fmaf(w, x1, acc1);
    acc2 = fmaf(w, x2, acc2); acc3 = fmaf(w, x3, acc3);
    acc4 = fmaf(w, x4, acc4); acc5 = fmaf(w, x5, acc5);
    acc6 = fmaf(w, x6, acc6); acc7 = fmaf(w, x7, acc7);
    u = un;
    o_nxt = o_p;
  }
  // merge the eight octets
  den += __shfl_xor(den, 8);  den += __shfl_xor(den, 16);  den += __shfl_xor(den, 32);
  acc0 += __shfl_xor(acc0, 8); acc0 += __shfl_xor(acc0, 16); acc0 += __shfl_xor(acc0, 32);
  acc1 += __shfl_xor(acc1, 8); acc1 += __shfl_xor(acc1, 16); acc1 += __shfl_xor(acc1, 32);
  acc2 += __shfl_xor(acc2, 8); acc2 += __shfl_xor(acc2, 16); acc2 += __shfl_xor(acc2, 32);
  acc3 += __shfl_xor(acc3, 8); acc3 += __shfl_xor(acc3, 16); acc3 += __shfl_xor(acc3, 32);
  acc4 += __shfl_xor(acc4, 8); acc4 += __shfl_xor(acc4, 16); acc4 += __shfl_xor(acc4, 32);
  acc5 += __shfl_xor(acc5, 8); acc5 += __shfl_xor(acc5, 16); acc5 += __shfl_xor(acc5, 32);
  acc6 += __shfl_xor(acc6, 8); acc6 += __shfl_xor(acc6, 16); acc6 += __shfl_xor(acc6, 32);
  acc7 += __shfl_xor(acc7, 8); acc7 += __shfl_xor(acc7, 16); acc7 += __shfl_xor(acc7, 32);
  float inv = __builtin_amdgcn_rcpf(den + 1e-16f);
  if (lane < 5) {  // lanes 0..4 cover channels 0..39
    uint4 bb = *(const uint4*)((const char*)bias + cb);
    float v0 = acc0 * inv + blo(bb.x), v1 = acc1 * inv + bhi(bb.x);
    float v2 = acc2 * inv + blo(bb.y), v3 = acc3 * inv + bhi(bb.y);
    float v4 = acc4 * inv + blo(bb.z), v5 = acc5 * inv + bhi(bb.z);
    float v6 = acc6 * inv + blo(bb.w), v7 = acc7 * inv + bhi(bb.w);
    int c0 = lane * 8;
    if (*flagp) {
      float* op = (float*)out + (size_t)wv * OUTD + c0;
      float4 f0 = {v0, v1, v2, v3};
      float4 f1 = {v4, v5, v6, v7};
      *(float4*)(op) = f0;
      *(float4*)(op + 4) = f1;
    } else {
      uint4 pk;
      pk.x = (unsigned int)f2bf(v0) | ((unsigned int)f2bf(v1) << 16);
      pk.y = (unsigned int)f2bf(v2) | ((unsigned int)f2bf(v3) << 16);
      pk.z = (unsigned int)f2bf(v4) | ((unsigned int)f2bf(v5) << 16);
      pk.w = (unsigned int)f2bf(v6) | ((unsigned int)f2bf(v7) << 16);
      *(uint4*)((unsigned short*)out + (size_t)wv * OUTD + c0) = pk;
    }
  }
}

extern "C" void kernel_launch(void* const* d_in, const int* in_sizes, int n_in,
                              void* d_out, int out_size, void* d_ws, size_t ws_size,
                              hipStream_t stream) {
  const void* x = d_in[0];
  const void* ei = d_in[1];

  char* ws = (char*)d_ws;
  size_t o = 0;
  auto alloc = [&](size_t bytes) {
    void* p = ws + o;
    o = (o + bytes + 255) & ~(size_t)255;
    return p;
  };
  int* flags = (int*)alloc(256);
  int* src_sorted = (int*)alloc((size_t)EE * 4);
  int* offs = (int*)alloc((size_t)(NN + 1) * 4);
  int* bcur = (int*)alloc((size_t)NBUCK * 16 * 4);
  unsigned int* bedges = (unsigned int*)alloc((size_t)NBUCK * BCAP * 4);
  unsigned short* F_W0 = (unsigned short*)alloc(2048 * 16);
  unsigned short* F_W1l = (unsigned short*)alloc(2048 * 16);
  unsigned short* F_W1r = (unsigned short*)alloc(2048 * 16);
  unsigned short* F_W2l = (unsigned short*)alloc(2048 * 16);
  unsigned short* F_W2r = (unsigned short*)alloc(2048 * 16);
  unsigned short* F_W3l = (unsigned short*)alloc(1024 * 16);
  unsigned short* F_W3r = (unsigned short*)alloc(1024 * 16);
  unsigned short* pblk = (unsigned short*)alloc(4096);
  unsigned short* ident = (unsigned short*)alloc((size_t)NN * 128 * 2);  // x0 -> x1
  unsigned short* bxlA = (unsigned short*)alloc((size_t)NN * 128 * 2);
  unsigned short* bxrA = (unsigned short*)alloc((size_t)NN * 128 * 2);
  unsigned short* bxlB = (unsigned short*)alloc((size_t)NN * 128 * 2);
  unsigned short* bxrB = (unsigned short*)alloc((size_t)NN * 128 * 2);
  (void)ws_size;

  unsigned short* pb0 = pblk;
  unsigned short* pb1l = pblk + 128;
  unsigned short* pb1r = pblk + 256;
  unsigned short* patt1 = pblk + 384;
  unsigned short* pbias1 = pblk + 512;
  unsigned short* pg1 = pblk + 640;
  unsigned short* pbe1 = pblk + 768;
  unsigned short* pb2l = pblk + 896;
  unsigned short* pb2r = pblk + 1024;
  unsigned short* patt2 = pblk + 1152;
  unsigned short* pbias2 = pblk + 1280;
  unsigned short* pg2 = pblk + 1408;
  unsigned short* pbe2 = pblk + 1536;
  unsigned short* pb3l = pblk + 1664;   // cap 64 (zero-padded)
  unsigned short* pb3r = pblk + 1728;   // cap 64
  unsigned short* patt3 = pblk + 1792;  // cap 64
  unsigned short* pbias3 = pblk + 1856; // cap 64

  // ---- init: weights + params + flags + bucket cursors ----
  WDescs wd;
  wd.d[0] = {d_in[2], F_W0, 8, 128};
  wd.d[1] = {d_in[4], F_W1l, 8, 128};
  wd.d[2] = {d_in[6], F_W1r, 8, 128};
  wd.d[3] = {d_in[12], F_W2l, 8, 128};
  wd.d[4] = {d_in[14], F_W2r, 8, 128};
  wd.d[5] = {d_in[20], F_W3l, 4, 40};  // T=4 -> 64 padded cols
  wd.d[6] = {d_in[22], F_W3r, 4, 40};
  int cum[8] = {0, 2048, 4096, 6144, 8192, 10240, 11264, 12288};
  for (int i = 0; i < 8; ++i) wd.cum[i] = cum[i];
  PCvs P;
  P.a[0] = {d_in[3], pb0, 128, 128};
  P.a[1] = {d_in[5], pb1l, 128, 128};
  P.a[2] = {d_in[7], pb1r, 128, 128};
  P.a[3] = {d_in[8], patt1, 128, 128};
  P.a[4] = {d_in[9], pbias1, 128, 128};
  P.a[5] = {d_in[10], pg1, 128, 128};
  P.a[6] = {d_in[11], pbe1, 128, 128};
  P.a[7] = {d_in[13], pb2l, 128, 128};
  P.a[8] = {d_in[15], pb2r, 128, 128};
  P.a[9] = {d_in[16], patt2, 128, 128};
  P.a[10] = {d_in[17], pbias2, 128, 128};
  P.a[11] = {d_in[18], pg2, 128, 128};
  P.a[12] = {d_in[19], pbe2, 128, 128};
  P.a[13] = {d_in[21], pb3l, 40, 64};
  P.a[14] = {d_in[23], pb3r, 40, 64};
  P.a[15] = {d_in[24], patt3, 40, 64};
  P.a[16] = {d_in[25], pbias3, 40, 64};
  init_kernel<<<66, 256, 0, stream>>>(ei, x, flags, bcur, wd, P);

  const int* fx = flags + 1;
  const int gb8 = (NN + 127) / 128;   // 391 blocks, 8 waves each, 16 rows/wave
  const int eb = (NN + 3) / 4;        // 12500 blocks, 1 wave/dst (edge_out)
  const int eb2 = (NN / 2 + 3) / 4;   // 6250 blocks, 2 dsts/wave (edge_hid)

  // ---- fused pass 1: edge bucket scatter || identity GEMM (W0 -> ident) ----
  GArgs gi; gi.s[0] = {F_W0, pb0, ident};
  gi.s[1] = {nullptr, nullptr, nullptr}; gi.s[2] = {nullptr, nullptr, nullptr};
  fused_scatter_gemm<<<ABLKS + gb8, 512, 0, stream>>>(ei, bedges, bcur, x, fx, gi, 1,
                                                      NN, 8, 128);

  // ---- fused pass 2: per-bucket sort || layer-1 l/r GEMM (W1l,W1r -> A pair) ----
  GArgs g1a; g1a.s[0] = {F_W1l, pb1l, bxlA}; g1a.s[1] = {F_W1r, pb1r, bxrA};
  g1a.s[2] = {nullptr, nullptr, nullptr};
  fused_sort_gemm<<<NBUCK + gb8, 512, 0, stream>>>(bedges, bcur, offs, src_sorted, x,
                                                   fx, g1a, 2, NN, 8, 128);

  // ---- layer 1 aggregation + fused layer-2 GEMM (reads A pair, writes B pair) ----
  edge_hid_kernel<8, 128, 1><<<eb2, 256, 0, stream>>>(
      bxlA, bxrA, patt1, pbias1, pg1, pbe1, ident, ident, offs, src_sorted,
      F_W2l, F_W2r, pb2l, pb2r, bxlB, bxrB);

  // ---- layer 2 aggregation + fused layer-3 GEMM (reads B pair, writes A pair) ----
  edge_hid_kernel<4, 64, 0><<<eb2, 256, 0, stream>>>(
      bxlB, bxrB, patt2, pbias2, pg2, pbe2, ident, ident, offs, src_sorted,
      F_W3l, F_W3r, pb3l, pb3r, bxlA, bxrA);

  // ---- layer 3 aggregation (64-ch padded rows in A pair) ----
  edge_out_kernel<<<eb, 256, 0, stream>>>(bxlA, bxrA, patt3, pbias3, d_out, fx, offs,
                                          src_sorted);
}

// Round 5
// 295.858 us; speedup vs baseline: 1.0895x; 1.0362x over previous
//
#include <hip/hip_runtime.h>
#include <hip/hip_bf16.h>

#define NN 50000
#define EE 800000
#define OUTD 40
#define NBUCK 196   // dst >> 8 buckets (50000/256 -> 0..195)
#define BCAP 8192   // slots per bucket (avg fill ~4082)
#define ABLKS 400   // scatter blocks (>= 1.5 per CU)
#define EPB 2000    // edges per scatter block

typedef __attribute__((ext_vector_type(8))) short short8;
typedef __attribute__((ext_vector_type(4))) float floatx4;

__device__ __forceinline__ float bf2f(unsigned short u) {
  union { unsigned int i; float f; } v; v.i = ((unsigned int)u) << 16; return v.f;
}
__device__ __forceinline__ unsigned short f2bf(float f) {
  union { float f; unsigned int i; } v; v.f = f;
  unsigned int x = v.i;
  return (unsigned short)((x + 0x7fffu + ((x >> 16) & 1u)) >> 16);  // RNE, finite-only
}
__device__ __forceinline__ float blo(unsigned int u) {
  union { unsigned int i; float f; } v; v.i = u << 16; return v.f;
}
__device__ __forceinline__ float bhi(unsigned int u) {
  union { unsigned int i; float f; } v; v.i = u & 0xffff0000u; return v.f;
}

template <int CTRL>
__device__ __forceinline__ float dpp_add(float x) {
  int y = __builtin_amdgcn_update_dpp(0, __float_as_int(x), CTRL, 0xF, 0xF, true);
  return x + __int_as_float(y);
}

// tanh-approx GELU (max abs err ~1e-3, well inside bf16 tolerance)
__device__ __forceinline__ float gelu1(float y) {
  float y2 = y * y;
  float z = y * fmaf(0.0356774081f, y2, 0.7978845608f);
  float e = __expf(-2.f * z);
  float r = __builtin_amdgcn_rcpf(1.f + e);
  float th = fmaf(2.f, r, -1.f);
  return y * fmaf(0.5f, th, 0.5f);
}

// clamp edge index into [0, last]
__device__ __forceinline__ int clampe(int i, int last) {
  int r = i <= last ? i : last;
  return r < 0 ? 0 : r;
}

// wave-local dtype probes (same 512B window everywhere -> identical result)
__device__ __forceinline__ int probe_f32(const void* x) {
  int lane = threadIdx.x & 63;
  unsigned short u = ((const unsigned short*)x)[2 * lane];
  int exf = (u >> 7) & 0xFF;
  unsigned long long b = __ballot((exf >= 100 && exf <= 142) ? 1 : 0);
  return (__popcll(b) >= 48) ? 0 : 1;
}
__device__ __forceinline__ int probe_i64(const void* ei) {
  int lane = threadIdx.x & 63;
  long long v = ((const long long*)ei)[lane];
  unsigned long long b = __ballot((v >= 0 && v < NN) ? 1 : 0);
  return (__popcll(b) >= 48) ? 1 : 0;
}

// ---------------- weight rearrange + param convert descriptors ----------------
struct WDesc { const void* W; unsigned short* F; int T; int ncols; };
struct WDescs { WDesc d[7]; int cum[8]; };
struct PCv { const void* s; unsigned short* d; int n; int cap; };
struct PCvs { PCv a[17]; };

// ---------------- init: weights + params + flags + bucket-cursor zero ----------------
__global__ __launch_bounds__(256) void init_kernel(const void* __restrict__ ei,
                                                   const void* __restrict__ x,
                                                   int* __restrict__ flags,
                                                   int* __restrict__ bcur,
                                                   WDescs ds, PCvs P) {
  int b = blockIdx.x;
  int f32 = probe_f32(x);
  if (b < 48) {
    int idx = b * 256 + threadIdx.x;
    if (idx >= 12288) return;
    int mi = 0;
    while (idx >= ds.cum[mi + 1]) mi++;
    int local = idx - ds.cum[mi];
    WDesc d = ds.d[mi];
    int lane = local & 63;
    int rest = local >> 6;
    int t = rest % d.T;
    int kb = rest / d.T;
    int m = lane & 15, quad = lane >> 4;
    int col = t * 16 + m;
    short8 v;
    for (int j = 0; j < 8; ++j) {
      int k = kb * 32 + quad * 8 + j;
      if (col < d.ncols) {
        int off = k * d.ncols + col;
        v[j] = f32 ? (short)f2bf(((const float*)d.W)[off])
                   : (short)((const unsigned short*)d.W)[off];
      } else {
        v[j] = 0;
      }
    }
    *(short8*)(d.F + (size_t)local * 8) = v;
  } else if (b < 65) {
    PCv p = P.a[b - 48];
    for (int i = threadIdx.x; i < p.cap; i += 256) {
      unsigned short o = 0;
      if (i < p.n)
        o = f32 ? f2bf(((const float*)p.s)[i]) : ((const unsigned short*)p.s)[i];
      p.d[i] = o;
    }
  } else {
    for (int i = threadIdx.x; i < NBUCK * 16; i += 256) bcur[i] = 0;
    if (threadIdx.x < 64) {
      int i64 = probe_i64(ei);
      if (threadIdx.x == 0) {
        flags[0] = i64;
        flags[1] = f32;
        flags[2] = 0;
      }
    }
  }
}

// ---------------- multi-output GEMM body: Out_i[M,ncols] = A[M,128] @ W_i + b_i ----
struct GSet { const unsigned short* F; const unsigned short* bias; unsigned short* Out; };
struct GArgs { GSet s[3]; };

__device__ __forceinline__ short8 pack_f4(float4 u0, float4 u1) {
  short8 r;
  r[0] = (short)f2bf(u0.x); r[1] = (short)f2bf(u0.y);
  r[2] = (short)f2bf(u0.z); r[3] = (short)f2bf(u0.w);
  r[4] = (short)f2bf(u1.x); r[5] = (short)f2bf(u1.y);
  r[6] = (short)f2bf(u1.z); r[7] = (short)f2bf(u1.w);
  return r;
}

__device__ __forceinline__ void gemm_body(int wave, int lane, const void* __restrict__ A,
                                          int f32, const GArgs& g, int nset, int M,
                                          int T, int ncols) {
  int r0 = wave * 16;
  if (r0 >= M) return;
  int m = lane & 15, quad = lane >> 4;
  short8 a0, a1, a2, a3;
  if (!f32) {
    const unsigned short* ar = (const unsigned short*)A + (size_t)(r0 + m) * 128 + quad * 8;
    a0 = *(const short8*)(ar);
    a1 = *(const short8*)(ar + 32);
    a2 = *(const short8*)(ar + 64);
    a3 = *(const short8*)(ar + 96);
  } else {
    const float* ar = (const float*)A + (size_t)(r0 + m) * 128 + quad * 8;
    a0 = pack_f4(*(const float4*)(ar), *(const float4*)(ar + 4));
    a1 = pack_f4(*(const float4*)(ar + 32), *(const float4*)(ar + 36));
    a2 = pack_f4(*(const float4*)(ar + 64), *(const float4*)(ar + 68));
    a3 = pack_f4(*(const float4*)(ar + 96), *(const float4*)(ar + 100));
  }
  size_t kstride = (size_t)T * 64 * 8;
  for (int si = 0; si < nset; ++si) {
    const unsigned short* F = g.s[si].F;
    const unsigned short* bias = g.s[si].bias;
    unsigned short* Out = g.s[si].Out;
    for (int t = 0; t < T; ++t) {
      floatx4 acc = {0.f, 0.f, 0.f, 0.f};
      const unsigned short* wp = F + ((size_t)t * 64 + lane) * 8;
      acc = __builtin_amdgcn_mfma_f32_16x16x32_bf16(a0, *(const short8*)(wp), acc, 0, 0, 0);
      acc = __builtin_amdgcn_mfma_f32_16x16x32_bf16(a1, *(const short8*)(wp + kstride), acc, 0, 0, 0);
      acc = __builtin_amdgcn_mfma_f32_16x16x32_bf16(a2, *(const short8*)(wp + 2 * kstride), acc, 0, 0, 0);
      acc = __builtin_amdgcn_mfma_f32_16x16x32_bf16(a3, *(const short8*)(wp + 3 * kstride), acc, 0, 0, 0);
      int col = t * 16 + m;
      if (col < ncols) {
        float bb = bf2f(bias[col]);
        for (int r = 0; r < 4; ++r) {
          int row = r0 + quad * 4 + r;
          Out[(size_t)row * ncols + col] = f2bf(acc[r] + bb);
        }
      }
    }
  }
}

// ---------------- fused: scatter (blocks < ABLKS) || layer-1 identity GEMM ----------
__global__ __launch_bounds__(512) void fused_scatter_gemm(
    const void* __restrict__ ei, unsigned int* __restrict__ bedges,
    int* __restrict__ bcur, const void* __restrict__ A,
    const int* __restrict__ flagp, GArgs g, int nset, int M, int T, int ncols) {
  __shared__ int lhist[NBUCK];
  __shared__ int lbase[NBUCK];
  if (blockIdx.x >= ABLKS) {
    int wave = (blockIdx.x - ABLKS) * 8 + (threadIdx.x >> 6);
    gemm_body(wave, threadIdx.x & 63, A, *flagp, g, nset, M, T, ncols);
    return;
  }
  int tid = threadIdx.x;
  if (tid < NBUCK) lhist[tid] = 0;
  int i64 = probe_i64(ei);
  __syncthreads();
  int e0 = blockIdx.x * EPB;
  int e1 = e0 + EPB; if (e1 > EE) e1 = EE;
  // phase 1: local histogram of dst bins
  for (int e = e0 + tid; e < e1; e += 512) {
    int d = i64 ? (int)((const long long*)ei)[EE + e] : ((const int*)ei)[EE + e];
    d = d < 0 ? 0 : (d >= NN ? NN - 1 : d);
    atomicAdd(&lhist[d >> 8], 1);
  }
  __syncthreads();
  // phase 2: one global reservation per bin
  if (tid < NBUCK) {
    int c = lhist[tid];
    lbase[tid] = c ? atomicAdd(&bcur[tid * 16], c) : 0;  // cursors padded to 64B
    lhist[tid] = 0;                                      // reuse as local cursor
  }
  __syncthreads();
  // phase 3: ranked scatter
  for (int e = e0 + tid; e < e1; e += 512) {
    int s, d;
    if (i64) {
      s = (int)((const long long*)ei)[e];
      d = (int)((const long long*)ei)[EE + e];
    } else {
      s = ((const int*)ei)[e];
      d = ((const int*)ei)[EE + e];
    }
    s = s < 0 ? 0 : (s >= NN ? NN - 1 : s);
    d = d < 0 ? 0 : (d >= NN ? NN - 1 : d);
    int bin = d >> 8;
    int r = atomicAdd(&lhist[bin], 1);
    int pos = lbase[bin] + r;
    if (pos < BCAP)
      bedges[(size_t)bin * BCAP + pos] =
          ((unsigned int)(d & 0xFF) << 24) | ((unsigned int)s << 8);
  }
}

// ---------------- fused: per-bucket dst sort (blocks < NBUCK) || layer-1 l/r GEMM ----
__global__ __launch_bounds__(512) void fused_sort_gemm(
    const unsigned int* __restrict__ bedges, const int* __restrict__ bcur,
    int* __restrict__ offs, int* __restrict__ src_sorted,
    const void* __restrict__ A, const int* __restrict__ flagp, GArgs g,
    int nset, int M, int T, int ncols) {
  __shared__ int lhist[256];
  __shared__ int lscan[256];
  __shared__ int lbin[256];
  __shared__ int sbase, scount, stotal;
  __shared__ unsigned int le[BCAP];
  __shared__ unsigned short lrank[BCAP];
  if (blockIdx.x >= NBUCK) {
    int wave = (blockIdx.x - NBUCK) * 8 + (threadIdx.x >> 6);
    gemm_body(wave, threadIdx.x & 63, A, *flagp, g, nset, M, T, ncols);
    return;
  }
  int k = blockIdx.x;
  int tid = threadIdx.x;
  if (tid < 256) {
    int c = 0;
    if (tid < NBUCK) {
      int v = bcur[tid * 16];
      c = v < BCAP ? v : BCAP;
    }
    lscan[tid] = c;
  }
  __syncthreads();
  for (int off = 1; off < 256; off <<= 1) {
    int u = 0;
    if (tid < 256 && tid >= off) u = lscan[tid - off];
    __syncthreads();
    if (tid < 256) lscan[tid] += u;
    __syncthreads();
  }
  if (tid == 0) {
    int pb = (k == 0) ? 0 : lscan[k - 1];
    sbase = pb;
    scount = lscan[k] - pb;
    stotal = lscan[NBUCK - 1];
  }
  if (tid < 256) lhist[tid] = 0;
  __syncthreads();
  int base = sbase, count = scount;
  const unsigned int* myb = bedges + (size_t)k * BCAP;
  for (int i = tid; i < count; i += 512) {
    unsigned int pk = myb[i];
    int bin = pk >> 24;
    int r = atomicAdd(&lhist[bin], 1);
    le[i] = pk;
    lrank[i] = (unsigned short)r;
  }
  __syncthreads();
  int hc = 0;
  if (tid < 256) {
    hc = lhist[tid];
    lscan[tid] = hc;
  }
  __syncthreads();
  for (int off = 1; off < 256; off <<= 1) {
    int u = 0;
    if (tid < 256 && tid >= off) u = lscan[tid - off];
    __syncthreads();
    if (tid < 256) lscan[tid] += u;
    __syncthreads();
  }
  if (tid < 256) {
    int binoff = lscan[tid] - hc;  // exclusive within bucket
    lbin[tid] = binoff;
    int node = k * 256 + tid;
    if (node < NN) offs[node] = base + binoff;
    if (k == 0 && tid == 0) offs[NN] = stotal;
  }
  __syncthreads();
  for (int i = tid; i < count; i += 512) {
    unsigned int pk = le[i];
    int bin = pk >> 24;
    int pos = base + lbin[bin] + (int)lrank[i];
    src_sorted[pos] = (int)(pk & 0x00FFFF00u);  // src<<8 byte offset
  }
}

// ---------------- edge aggregation, hidden layers (H=4, C=32) ----------------
// Main loop at the compulsory cross-XCD L2-fill roofline (~90 MB @ ~2.3 TB/s).
// 512 threads / 8 waves / 16 dsts per block. FUSED EPILOGUE: the block's 16
// finished x-rows form a FULL 16x128 MFMA tile in LDS (272B row stride kills
// the bank conflicts seen at 256B) and the next layer's row-local GEMM runs
// here — no standalone gemm2/gemm3 dispatches, no zero-row MFMA waste, and
// half the per-block weight re-fetch vs the 8-row version.
// TT = weight tiles (8 -> 128 cols, 4 -> 64 cols); WRITEX: materialize x row.
template <int TT, int NCOLS, int WRITEX>
__global__ __launch_bounds__(512) void edge_hid_kernel(
    const unsigned short* __restrict__ xl, const unsigned short* __restrict__ xr,
    const unsigned short* __restrict__ att, const unsigned short* __restrict__ bias,
    const unsigned short* __restrict__ gamma, const unsigned short* __restrict__ beta,
    const unsigned short* __restrict__ resid, unsigned short* __restrict__ xout,
    const int* __restrict__ offs, const int* __restrict__ srcs,
    const unsigned short* __restrict__ Fl, const unsigned short* __restrict__ Fr,
    const unsigned short* __restrict__ bl, const unsigned short* __restrict__ br,
    unsigned short* __restrict__ outl, unsigned short* __restrict__ outr) {
  __shared__ unsigned short sA[16 * 136];  // 16 real rows, 272B stride (+pad)
  const int wid = threadIdx.x >> 6;
  int wpair = blockIdx.x * 8 + wid;
  int lane = threadIdx.x & 63;
  int half = lane >> 5;
  int wv = wpair * 2 + half;
  // NN % 16 == 0 and grid covers it exactly -> no early returns,
  // so the epilogue __syncthreads below is safe.
  int hl = lane & 31;
  int sub = hl >> 4;          // edge slot (0/1) within this half
  int cb = (hl & 15) * 16;    // byte offset of this lane's 8 channels (256 B/row)
  int beg = offs[wv], end = offs[wv + 1], last = end - 1;
  int iters = (end - beg + 1) >> 1;  // ceil(deg/2)
  int oi = __shfl_xor(iters, 32);
  int maxit = __builtin_amdgcn_readfirstlane(iters > oi ? iters : oi);
  const char* xlb = (const char*)xl;
  int c0 = hl * 4;
  // hoisted epilogue load: resid row latency hides under the whole edge loop
  uint2 rr = *(const uint2*)(resid + (size_t)wv * 128 + c0);
  uint4 xr8 = *(const uint4*)((const char*)xr + (size_t)wv * 256 + cb);
  float rx0 = blo(xr8.x), rx1 = bhi(xr8.x), rx2 = blo(xr8.y), rx3 = bhi(xr8.y);
  float rx4 = blo(xr8.z), rx5 = bhi(xr8.z), rx6 = blo(xr8.w), rx7 = bhi(xr8.w);
  uint4 at8 = *(const uint4*)((const char*)att + cb);
  float a0 = blo(at8.x), a1 = bhi(at8.x), a2 = blo(at8.y), a3 = bhi(at8.y);
  float a4 = blo(at8.z), a5 = bhi(at8.z), a6 = blo(at8.w), a7 = bhi(at8.w);
  float acc0 = 0.f, acc1 = 0.f, acc2 = 0.f, acc3 = 0.f;
  float acc4 = 0.f, acc5 = 0.f, acc6 = 0.f, acc7 = 0.f, den = 0.f;
  // pipeline prologue: index for edge 0 and edge 1, gather for edge 0
  int ir = beg + sub;
  int o_cur = srcs[clampe(ir, last)];
  int o_nxt = srcs[clampe(ir + 2, last)];
  uint4 u = *(const uint4*)(xlb + (o_cur + cb));
  for (int it = 0; it < maxit; ++it) {
    int o_p = srcs[clampe(ir + 4, last)];
    uint4 un = *(const uint4*)(xlb + (o_nxt + cb));
    float mk = (ir <= last) ? 1.f : 0.f;
    ir += 2;
    float x0 = blo(u.x), x1 = bhi(u.x), x2 = blo(u.y), x3 = bhi(u.y);
    float x4 = blo(u.z), x5 = bhi(u.z), x6 = blo(u.w), x7 = bhi(u.w);
    float t0 = x0 + rx0, t1 = x1 + rx1, t2 = x2 + rx2, t3 = x3 + rx3;
    float t4 = x4 + rx4, t5 = x5 + rx5, t6 = x6 + rx6, t7 = x7 + rx7;
    float pa = a0 * t0;
    pa = fmaf(a1, t1, pa); pa = fmaf(a2, t2, pa); pa = fmaf(a3, t3, pa);
    pa = fmaf(a4, t4, pa); pa = fmaf(a5, t5, pa); pa = fmaf(a6, t6, pa); pa = fmaf(a7, t7, pa);
    float pb = a0 * fabsf(t0);
    pb = fmaf(a1, fabsf(t1), pb); pb = fmaf(a2, fabsf(t2), pb); pb = fmaf(a3, fabsf(t3), pb);
    pb = fmaf(a4, fabsf(t4), pb); pb = fmaf(a5, fabsf(t5), pb);
    pb = fmaf(a6, fabsf(t6), pb); pb = fmaf(a7, fabsf(t7), pb);
    float p = fmaf(0.4f, pb, 0.6f * pa);
    p = dpp_add<0xB1>(p);  // quad xor1
    p = dpp_add<0x4E>(p);  // quad xor2 -> 4-lane head sum (32 ch)
    float w = __expf(fminf(p, 60.f)) * mk;
    den += w;
    acc0 = fmaf(w, x0, acc0); acc1 = fmaf(w, x1, acc1);
    acc2 = fmaf(w, x2, acc2); acc3 = fmaf(w, x3, acc3);
    acc4 = fmaf(w, x4, acc4); acc5 = fmaf(w, x5, acc5);
    acc6 = fmaf(w, x6, acc6); acc7 = fmaf(w, x7, acc7);
    u = un;
    o_nxt = o_p;
  }
  // merge the two edge slots within each half (xor16 stays inside the half)
  den += __shfl_xor(den, 16);
  acc0 += __shfl_xor(acc0, 16); acc1 += __shfl_xor(acc1, 16);
  acc2 += __shfl_xor(acc2, 16); acc3 += __shfl_xor(acc3, 16);
  acc4 += __shfl_xor(acc4, 16); acc5 += __shfl_xor(acc5, 16);
  acc6 += __shfl_xor(acc6, 16); acc7 += __shfl_xor(acc7, 16);
  // redistribute to 4 ch/lane within each half (32 lanes per dst)
  int srcLane = (half << 5) + (hl >> 1);
  float b0 = __shfl(acc0, srcLane), b1 = __shfl(acc1, srcLane);
  float b2 = __shfl(acc2, srcLane), b3 = __shfl(acc3, srcLane);
  float h4 = __shfl(acc4, srcLane), h5 = __shfl(acc5, srcLane);
  float h6 = __shfl(acc6, srcLane), h7 = __shfl(acc7, srcLane);
  float dn = __shfl(den, srcLane);
  bool hi = (hl & 1) != 0;
  float v0 = hi ? h4 : b0, v1 = hi ? h5 : b1, v2 = hi ? h6 : b2, v3 = hi ? h7 : b3;
  float inv = __builtin_amdgcn_rcpf(dn + 1e-16f);
  uint2 bb = *(const uint2*)(bias + c0);
  float o0 = v0 * inv + blo(bb.x), o1 = v1 * inv + bhi(bb.x);
  float o2 = v2 * inv + blo(bb.y), o3 = v3 * inv + bhi(bb.y);
  // LayerNorm over 128 ch: 32-lane reduction within each half
  float s = (o0 + o1) + (o2 + o3);
  for (int k = 1; k < 32; k <<= 1) s += __shfl_xor(s, k);
  float mu = s * (1.f / 128.f);
  float d0 = o0 - mu, d1 = o1 - mu, d2 = o2 - mu, d3 = o3 - mu;
  float q = (d0 * d0 + d1 * d1) + (d2 * d2 + d3 * d3);
  for (int k = 1; k < 32; k <<= 1) q += __shfl_xor(q, k);
  float rstd = rsqrtf(q * (1.f / 128.f) + 1e-5f);
  uint2 gg = *(const uint2*)(gamma + c0);
  uint2 be = *(const uint2*)(beta + c0);
  float y0 = d0 * rstd * blo(gg.x) + blo(be.x);
  float y1 = d1 * rstd * bhi(gg.x) + bhi(be.x);
  float y2 = d2 * rstd * blo(gg.y) + blo(be.y);
  float y3 = d3 * rstd * bhi(gg.y) + bhi(be.y);
  y0 = gelu1(y0); y1 = gelu1(y1); y2 = gelu1(y2); y3 = gelu1(y3);
  y0 += blo(rr.x); y1 += bhi(rr.x); y2 += blo(rr.y); y3 += bhi(rr.y);
  uint2 pk;
  pk.x = (unsigned int)f2bf(y0) | ((unsigned int)f2bf(y1) << 16);
  pk.y = (unsigned int)f2bf(y2) | ((unsigned int)f2bf(y3) << 16);
  if (WRITEX) *(uint2*)(xout + (size_t)wv * 128 + c0) = pk;

  // ---- fused row-local GEMM epilogue: Out{l,r}[row] = x_row @ W{l,r} + b ----
  int lrow = wid * 2 + half;                 // 0..15 local row = full MFMA tile
  *(uint2*)(&sA[lrow * 136 + c0]) = pk;      // stage bf16 row (272B stride)
  __syncthreads();
  int m = lane & 15, quad = lane >> 4;
  const unsigned short* arow = sA + m * 136 + quad * 8;
  short8 A0 = *(const short8*)(arow);
  short8 A1 = *(const short8*)(arow + 32);
  short8 A2 = *(const short8*)(arow + 64);
  short8 A3 = *(const short8*)(arow + 96);
  const size_t kst = (size_t)TT * 64 * 8;
  const int rowbase = blockIdx.x * 16;
  constexpr int PER = (2 * TT) / 8;  // tile-columns per wave (l and r mats)
#pragma unroll
  for (int jj = 0; jj < PER; ++jj) {
    int j = wid * PER + jj;
    bool isr = j >= TT;
    const unsigned short* F = isr ? Fr : Fl;
    const unsigned short* bs = isr ? br : bl;
    unsigned short* Out = isr ? outr : outl;
    int t = isr ? j - TT : j;
    floatx4 acc = {0.f, 0.f, 0.f, 0.f};
    const unsigned short* wp = F + ((size_t)t * 64 + lane) * 8;
    acc = __builtin_amdgcn_mfma_f32_16x16x32_bf16(A0, *(const short8*)(wp), acc, 0, 0, 0);
    acc = __builtin_amdgcn_mfma_f32_16x16x32_bf16(A1, *(const short8*)(wp + kst), acc, 0, 0, 0);
    acc = __builtin_amdgcn_mfma_f32_16x16x32_bf16(A2, *(const short8*)(wp + 2 * kst), acc, 0, 0, 0);
    acc = __builtin_amdgcn_mfma_f32_16x16x32_bf16(A3, *(const short8*)(wp + 3 * kst), acc, 0, 0, 0);
    int col = t * 16 + m;
    float bbv = bf2f(bs[col]);
#pragma unroll
    for (int r = 0; r < 4; ++r)
      Out[(size_t)(rowbase + quad * 4 + r) * NCOLS + col] = f2bf(acc[r] + bbv);
  }
}

// ---------------- edge aggregation, output layer (padded to 64 ch) ----------------
__global__ __launch_bounds__(256) void edge_out_kernel(
    const unsigned short* __restrict__ xl, const unsigned short* __restrict__ xr,
    const unsigned short* __restrict__ att, const unsigned short* __restrict__ bias,
    void* __restrict__ out, const int* __restrict__ flagp,
    const int* __restrict__ offs, const int* __restrict__ srcs) {
  int wv = blockIdx.x * 4 + (threadIdx.x >> 6);
  if (wv >= NN) return;
  int lane = threadIdx.x & 63;
  int oct = lane >> 3;
  int cb = (lane & 7) * 16;  // byte offset of 8 ch (8 lanes x 16B = 128B row)
  int beg = __builtin_amdgcn_readfirstlane(offs[wv]);
  int last = __builtin_amdgcn_readfirstlane(offs[wv + 1]) - 1;
  const char* xlb = (const char*)xl;
  uint4 xr8 = *(const uint4*)((const char*)xr + (size_t)wv * 128 + cb);
  float rx0 = blo(xr8.x), rx1 = bhi(xr8.x), rx2 = blo(xr8.y), rx3 = bhi(xr8.y);
  float rx4 = blo(xr8.z), rx5 = bhi(xr8.z), rx6 = blo(xr8.w), rx7 = bhi(xr8.w);
  uint4 at8 = *(const uint4*)((const char*)att + cb);
  float a0 = blo(at8.x), a1 = bhi(at8.x), a2 = blo(at8.y), a3 = bhi(at8.y);
  float a4 = blo(at8.z), a5 = bhi(at8.z), a6 = blo(at8.w), a7 = bhi(at8.w);
  float acc0 = 0.f, acc1 = 0.f, acc2 = 0.f, acc3 = 0.f;
  float acc4 = 0.f, acc5 = 0.f, acc6 = 0.f, acc7 = 0.f, den = 0.f;
  // pipeline prologue
  int ir = beg + oct;
  int o_cur = srcs[clampe(ir, last)];
  int o_nxt = srcs[clampe(ir + 8, last)];
  uint4 u = *(const uint4*)(xlb + ((o_cur >> 1) + cb));  // 64-ch rows = 128 B
  for (int e = beg; e <= last; e += 8) {
    int o_p = srcs[clampe(ir + 16, last)];
    uint4 un = *(const uint4*)(xlb + ((o_nxt >> 1) + cb));
    float mk = (ir <= last) ? 1.f : 0.f;
    ir += 8;
    float x0 = blo(u.x), x1 = bhi(u.x), x2 = blo(u.y), x3 = bhi(u.y);
    float x4 = blo(u.z), x5 = bhi(u.z), x6 = blo(u.w), x7 = bhi(u.w);
    float t0 = x0 + rx0, t1 = x1 + rx1, t2 = x2 + rx2, t3 = x3 + rx3;
    float t4 = x4 + rx4, t5 = x5 + rx5, t6 = x6 + rx6, t7 = x7 + rx7;
    float pa = a0 * t0;
    pa = fmaf(a1, t1, pa); pa = fmaf(a2, t2, pa); pa = fmaf(a3, t3, pa);
    pa = fmaf(a4, t4, pa); pa = fmaf(a5, t5, pa); pa = fmaf(a6, t6, pa); pa = fmaf(a7, t7, pa);
    float pb = a0 * fabsf(t0);
    pb = fmaf(a1, fabsf(t1), pb); pb = fmaf(a2, fabsf(t2), pb); pb = fmaf(a3, fabsf(t3), pb);
    pb = fmaf(a4, fabsf(t4), pb); pb = fmaf(a5, fabsf(t5), pb);
    pb = fmaf(a6, fabsf(t6), pb); pb = fmaf(a7, fabsf(t7), pb);
    float p = fmaf(0.4f, pb, 0.6f * pa);
    p = dpp_add<0xB1>(p);   // xor1
    p = dpp_add<0x4E>(p);   // xor2
    p = dpp_add<0x141>(p);  // row_half_mirror -> 8-lane sum = 64-ch dot
    float w = __expf(fminf(p, 60.f)) * mk;
    den += w;
    acc0 = fmaf(w, x0, acc0); acc1 = fmaf(w, x1, acc1);
    acc2 = fmaf(w, x2, acc2); acc3 = fmaf(w, x3, acc3);
    acc4 = fmaf(w, x4, acc4); acc5 = fmaf(w, x5, acc5);
    acc6 = fmaf(w, x6, acc6); acc7 = fmaf(w, x7, acc7);
    u = un;
    o_nxt = o_p;
  }
  // merge the eight octets
  den += __shfl_xor(den, 8);  den += __shfl_xor(den, 16);  den += __shfl_xor(den, 32);
  acc0 += __shfl_xor(acc0, 8); acc0 += __shfl_xor(acc0, 16); acc0 += __shfl_xor(acc0, 32);
  acc1 += __shfl_xor(acc1, 8); acc1 += __shfl_xor(acc1, 16); acc1 += __shfl_xor(acc1, 32);
  acc2 += __shfl_xor(acc2, 8); acc2 += __shfl_xor(acc2, 16); acc2 += __shfl_xor(acc2, 32);
  acc3 += __shfl_xor(acc3, 8); acc3 += __shfl_xor(acc3, 16); acc3 += __shfl_xor(acc3, 32);
  acc4 += __shfl_xor(acc4, 8); acc4 += __shfl_xor(acc4, 16); acc4 += __shfl_xor(acc4, 32);
  acc5 += __shfl_xor(acc5, 8); acc5 += __shfl_xor(acc5, 16); acc5 += __shfl_xor(acc5, 32);
  acc6 += __shfl_xor(acc6, 8); acc6 += __shfl_xor(acc6, 16); acc6 += __shfl_xor(acc6, 32);
  acc7 += __shfl_xor(acc7, 8); acc7 += __shfl_xor(acc7, 16); acc7 += __shfl_xor(acc7, 32);
  float inv = __builtin_amdgcn_rcpf(den + 1e-16f);
  if (lane < 5) {  // lanes 0..4 cover channels 0..39
    uint4 bb = *(const uint4*)((const char*)bias + cb);
    float v0 = acc0 * inv + blo(bb.x), v1 = acc1 * inv + bhi(bb.x);
    float v2 = acc2 * inv + blo(bb.y), v3 = acc3 * inv + bhi(bb.y);
    float v4 = acc4 * inv + blo(bb.z), v5 = acc5 * inv + bhi(bb.z);
    float v6 = acc6 * inv + blo(bb.w), v7 = acc7 * inv + bhi(bb.w);
    int c0 = lane * 8;
    if (*flagp) {
      float* op = (float*)out + (size_t)wv * OUTD + c0;
      float4 f0 = {v0, v1, v2, v3};
      float4 f1 = {v4, v5, v6, v7};
      *(float4*)(op) = f0;
      *(float4*)(op + 4) = f1;
    } else {
      uint4 pk;
      pk.x = (unsigned int)f2bf(v0) | ((unsigned int)f2bf(v1) << 16);
      pk.y = (unsigned int)f2bf(v2) | ((unsigned int)f2bf(v3) << 16);
      pk.z = (unsigned int)f2bf(v4) | ((unsigned int)f2bf(v5) << 16);
      pk.w = (unsigned int)f2bf(v6) | ((unsigned int)f2bf(v7) << 16);
      *(uint4*)((unsigned short*)out + (size_t)wv * OUTD + c0) = pk;
    }
  }
}

extern "C" void kernel_launch(void* const* d_in, const int* in_sizes, int n_in,
                              void* d_out, int out_size, void* d_ws, size_t ws_size,
                              hipStream_t stream) {
  const void* x = d_in[0];
  const void* ei = d_in[1];

  char* ws = (char*)d_ws;
  size_t o = 0;
  auto alloc = [&](size_t bytes) {
    void* p = ws + o;
    o = (o + bytes + 255) & ~(size_t)255;
    return p;
  };
  int* flags = (int*)alloc(256);
  int* src_sorted = (int*)alloc((size_t)EE * 4);
  int* offs = (int*)alloc((size_t)(NN + 1) * 4);
  int* bcur = (int*)alloc((size_t)NBUCK * 16 * 4);
  unsigned int* bedges = (unsigned int*)alloc((size_t)NBUCK * BCAP * 4);
  unsigned short* F_W0 = (unsigned short*)alloc(2048 * 16);
  unsigned short* F_W1l = (unsigned short*)alloc(2048 * 16);
  unsigned short* F_W1r = (unsigned short*)alloc(2048 * 16);
  unsigned short* F_W2l = (unsigned short*)alloc(2048 * 16);
  unsigned short* F_W2r = (unsigned short*)alloc(2048 * 16);
  unsigned short* F_W3l = (unsigned short*)alloc(1024 * 16);
  unsigned short* F_W3r = (unsigned short*)alloc(1024 * 16);
  unsigned short* pblk = (unsigned short*)alloc(4096);
  unsigned short* ident = (unsigned short*)alloc((size_t)NN * 128 * 2);  // x0 -> x1
  unsigned short* bxlA = (unsigned short*)alloc((size_t)NN * 128 * 2);
  unsigned short* bxrA = (unsigned short*)alloc((size_t)NN * 128 * 2);
  unsigned short* bxlB = (unsigned short*)alloc((size_t)NN * 128 * 2);
  unsigned short* bxrB = (unsigned short*)alloc((size_t)NN * 128 * 2);
  (void)ws_size;

  unsigned short* pb0 = pblk;
  unsigned short* pb1l = pblk + 128;
  unsigned short* pb1r = pblk + 256;
  unsigned short* patt1 = pblk + 384;
  unsigned short* pbias1 = pblk + 512;
  unsigned short* pg1 = pblk + 640;
  unsigned short* pbe1 = pblk + 768;
  unsigned short* pb2l = pblk + 896;
  unsigned short* pb2r = pblk + 1024;
  unsigned short* patt2 = pblk + 1152;
  unsigned short* pbias2 = pblk + 1280;
  unsigned short* pg2 = pblk + 1408;
  unsigned short* pbe2 = pblk + 1536;
  unsigned short* pb3l = pblk + 1664;   // cap 64 (zero-padded)
  unsigned short* pb3r = pblk + 1728;   // cap 64
  unsigned short* patt3 = pblk + 1792;  // cap 64
  unsigned short* pbias3 = pblk + 1856; // cap 64

  // ---- init: weights + params + flags + bucket cursors ----
  WDescs wd;
  wd.d[0] = {d_in[2], F_W0, 8, 128};
  wd.d[1] = {d_in[4], F_W1l, 8, 128};
  wd.d[2] = {d_in[6], F_W1r, 8, 128};
  wd.d[3] = {d_in[12], F_W2l, 8, 128};
  wd.d[4] = {d_in[14], F_W2r, 8, 128};
  wd.d[5] = {d_in[20], F_W3l, 4, 40};  // T=4 -> 64 padded cols
  wd.d[6] = {d_in[22], F_W3r, 4, 40};
  int cum[8] = {0, 2048, 4096, 6144, 8192, 10240, 11264, 12288};
  for (int i = 0; i < 8; ++i) wd.cum[i] = cum[i];
  PCvs P;
  P.a[0] = {d_in[3], pb0, 128, 128};
  P.a[1] = {d_in[5], pb1l, 128, 128};
  P.a[2] = {d_in[7], pb1r, 128, 128};
  P.a[3] = {d_in[8], patt1, 128, 128};
  P.a[4] = {d_in[9], pbias1, 128, 128};
  P.a[5] = {d_in[10], pg1, 128, 128};
  P.a[6] = {d_in[11], pbe1, 128, 128};
  P.a[7] = {d_in[13], pb2l, 128, 128};
  P.a[8] = {d_in[15], pb2r, 128, 128};
  P.a[9] = {d_in[16], patt2, 128, 128};
  P.a[10] = {d_in[17], pbias2, 128, 128};
  P.a[11] = {d_in[18], pg2, 128, 128};
  P.a[12] = {d_in[19], pbe2, 128, 128};
  P.a[13] = {d_in[21], pb3l, 40, 64};
  P.a[14] = {d_in[23], pb3r, 40, 64};
  P.a[15] = {d_in[24], patt3, 40, 64};
  P.a[16] = {d_in[25], pbias3, 40, 64};
  init_kernel<<<66, 256, 0, stream>>>(ei, x, flags, bcur, wd, P);

  const int* fx = flags + 1;
  const int gb8 = (NN + 127) / 128;   // 391 blocks, 8 waves each, 16 rows/wave
  const int eb = (NN + 3) / 4;        // 12500 blocks, 1 wave/dst (edge_out)
  const int eb16 = NN / 16;           // 3125 blocks, 16 dsts/block (edge_hid)

  // ---- fused pass 1: edge bucket scatter || identity GEMM (W0 -> ident) ----
  GArgs gi; gi.s[0] = {F_W0, pb0, ident};
  gi.s[1] = {nullptr, nullptr, nullptr}; gi.s[2] = {nullptr, nullptr, nullptr};
  fused_scatter_gemm<<<ABLKS + gb8, 512, 0, stream>>>(ei, bedges, bcur, x, fx, gi, 1,
                                                      NN, 8, 128);

  // ---- fused pass 2: per-bucket sort || layer-1 l/r GEMM (W1l,W1r -> A pair) ----
  GArgs g1a; g1a.s[0] = {F_W1l, pb1l, bxlA}; g1a.s[1] = {F_W1r, pb1r, bxrA};
  g1a.s[2] = {nullptr, nullptr, nullptr};
  fused_sort_gemm<<<NBUCK + gb8, 512, 0, stream>>>(bedges, bcur, offs, src_sorted, x,
                                                   fx, g1a, 2, NN, 8, 128);

  // ---- layer 1 aggregation + fused layer-2 GEMM (reads A pair, writes B pair) ----
  edge_hid_kernel<8, 128, 1><<<eb16, 512, 0, stream>>>(
      bxlA, bxrA, patt1, pbias1, pg1, pbe1, ident, ident, offs, src_sorted,
      F_W2l, F_W2r, pb2l, pb2r, bxlB, bxrB);

  // ---- layer 2 aggregation + fused layer-3 GEMM (reads B pair, writes A pair) ----
  edge_hid_kernel<4, 64, 0><<<eb16, 512, 0, stream>>>(
      bxlB, bxrB, patt2, pbias2, pg2, pbe2, ident, ident, offs, src_sorted,
      F_W3l, F_W3r, pb3l, pb3r, bxlA, bxrA);

  // ---- layer 3 aggregation (64-ch padded rows in A pair) ----
  edge_out_kernel<<<eb, 256, 0, stream>>>(bxlA, bxrA, patt3, pbias3, d_out, fx, offs,
                                          src_sorted);
}

// Round 6
// 288.073 us; speedup vs baseline: 1.1189x; 1.0270x over previous
//
#include <hip/hip_runtime.h>
#include <hip/hip_bf16.h>

#define NN 50000
#define EE 800000
#define OUTD 40
#define NBUCK 196   // dst >> 8 buckets (50000/256 -> 0..195)
#define BCAP 8192   // slots per bucket (avg fill ~4082)
#define ABLKS 400   // scatter blocks (>= 1.5 per CU)
#define EPB 2000    // edges per scatter block

typedef __attribute__((ext_vector_type(8))) short short8;
typedef __attribute__((ext_vector_type(4))) float floatx4;

__device__ __forceinline__ float bf2f(unsigned short u) {
  union { unsigned int i; float f; } v; v.i = ((unsigned int)u) << 16; return v.f;
}
__device__ __forceinline__ unsigned short f2bf(float f) {
  union { float f; unsigned int i; } v; v.f = f;
  unsigned int x = v.i;
  return (unsigned short)((x + 0x7fffu + ((x >> 16) & 1u)) >> 16);  // RNE, finite-only
}
__device__ __forceinline__ float blo(unsigned int u) {
  union { unsigned int i; float f; } v; v.i = u << 16; return v.f;
}
__device__ __forceinline__ float bhi(unsigned int u) {
  union { unsigned int i; float f; } v; v.i = u & 0xffff0000u; return v.f;
}

template <int CTRL>
__device__ __forceinline__ float dpp_add(float x) {
  int y = __builtin_amdgcn_update_dpp(0, __float_as_int(x), CTRL, 0xF, 0xF, true);
  return x + __int_as_float(y);
}

// tanh-approx GELU (max abs err ~1e-3, well inside bf16 tolerance)
__device__ __forceinline__ float gelu1(float y) {
  float y2 = y * y;
  float z = y * fmaf(0.0356774081f, y2, 0.7978845608f);
  float e = __expf(-2.f * z);
  float r = __builtin_amdgcn_rcpf(1.f + e);
  float th = fmaf(2.f, r, -1.f);
  return y * fmaf(0.5f, th, 0.5f);
}

// clamp edge index into [0, last]
__device__ __forceinline__ int clampe(int i, int last) {
  int r = i <= last ? i : last;
  return r < 0 ? 0 : r;
}

// wave-local dtype probes (same 512B window everywhere -> identical result)
__device__ __forceinline__ int probe_f32(const void* x) {
  int lane = threadIdx.x & 63;
  unsigned short u = ((const unsigned short*)x)[2 * lane];
  int exf = (u >> 7) & 0xFF;
  unsigned long long b = __ballot((exf >= 100 && exf <= 142) ? 1 : 0);
  return (__popcll(b) >= 48) ? 0 : 1;
}
__device__ __forceinline__ int probe_i64(const void* ei) {
  int lane = threadIdx.x & 63;
  long long v = ((const long long*)ei)[lane];
  unsigned long long b = __ballot((v >= 0 && v < NN) ? 1 : 0);
  return (__popcll(b) >= 48) ? 1 : 0;
}

// ---------------- weight rearrange + param convert descriptors ----------------
struct WDesc { const void* W; unsigned short* F; int T; int ncols; };
struct WDescs { WDesc d[7]; int cum[8]; };
struct PCv { const void* s; unsigned short* d; int n; int cap; };
struct PCvs { PCv a[17]; };

// ---------------- multi-output GEMM body: Out_i[M,ncols] = A[M,128] @ W_i + b_i ----
struct GSet { const unsigned short* F; const unsigned short* bias; unsigned short* Out; };
struct GArgs { GSet s[3]; };

__device__ __forceinline__ short8 pack_f4(float4 u0, float4 u1) {
  short8 r;
  r[0] = (short)f2bf(u0.x); r[1] = (short)f2bf(u0.y);
  r[2] = (short)f2bf(u0.z); r[3] = (short)f2bf(u0.w);
  r[4] = (short)f2bf(u1.x); r[5] = (short)f2bf(u1.y);
  r[6] = (short)f2bf(u1.z); r[7] = (short)f2bf(u1.w);
  return r;
}

__device__ __forceinline__ void gemm_body(int wave, int lane, const void* __restrict__ A,
                                          int f32, const GArgs& g, int nset, int M,
                                          int T, int ncols) {
  int r0 = wave * 16;
  if (r0 >= M) return;
  int m = lane & 15, quad = lane >> 4;
  short8 a0, a1, a2, a3;
  if (!f32) {
    const unsigned short* ar = (const unsigned short*)A + (size_t)(r0 + m) * 128 + quad * 8;
    a0 = *(const short8*)(ar);
    a1 = *(const short8*)(ar + 32);
    a2 = *(const short8*)(ar + 64);
    a3 = *(const short8*)(ar + 96);
  } else {
    const float* ar = (const float*)A + (size_t)(r0 + m) * 128 + quad * 8;
    a0 = pack_f4(*(const float4*)(ar), *(const float4*)(ar + 4));
    a1 = pack_f4(*(const float4*)(ar + 32), *(const float4*)(ar + 36));
    a2 = pack_f4(*(const float4*)(ar + 64), *(const float4*)(ar + 68));
    a3 = pack_f4(*(const float4*)(ar + 96), *(const float4*)(ar + 100));
  }
  size_t kstride = (size_t)T * 64 * 8;
  for (int si = 0; si < nset; ++si) {
    const unsigned short* F = g.s[si].F;
    const unsigned short* bias = g.s[si].bias;
    unsigned short* Out = g.s[si].Out;
    for (int t = 0; t < T; ++t) {
      floatx4 acc = {0.f, 0.f, 0.f, 0.f};
      const unsigned short* wp = F + ((size_t)t * 64 + lane) * 8;
      acc = __builtin_amdgcn_mfma_f32_16x16x32_bf16(a0, *(const short8*)(wp), acc, 0, 0, 0);
      acc = __builtin_amdgcn_mfma_f32_16x16x32_bf16(a1, *(const short8*)(wp + kstride), acc, 0, 0, 0);
      acc = __builtin_amdgcn_mfma_f32_16x16x32_bf16(a2, *(const short8*)(wp + 2 * kstride), acc, 0, 0, 0);
      acc = __builtin_amdgcn_mfma_f32_16x16x32_bf16(a3, *(const short8*)(wp + 3 * kstride), acc, 0, 0, 0);
      int col = t * 16 + m;
      if (col < ncols) {
        float bb = bf2f(bias[col]);
        for (int r = 0; r < 4; ++r) {
          int row = r0 + quad * 4 + r;
          Out[(size_t)row * ncols + col] = f2bf(acc[r] + bb);
        }
      }
    }
  }
}

// ---------------- fused pass 1: scatter (blocks < ABLKS) || init work ----------
// init work (42 extra blocks): weight rearrange (24), param convert (17),
// flags (1). bcur is zeroed by hipMemsetAsync before this launch.
__global__ __launch_bounds__(512) void fused_scatter_init(
    const void* __restrict__ ei, const void* __restrict__ x,
    unsigned int* __restrict__ bedges, int* __restrict__ bcur,
    int* __restrict__ flags, WDescs ds, PCvs P) {
  __shared__ int lhist[NBUCK];
  __shared__ int lbase[NBUCK];
  if (blockIdx.x >= ABLKS) {
    int b = blockIdx.x - ABLKS;
    int tid = threadIdx.x;
    int f32 = probe_f32(x);
    if (b < 24) {  // weight rearrange: idx in [0, 12288)
      int idx = b * 512 + tid;
      if (idx >= 12288) return;
      int mi = 0;
      while (idx >= ds.cum[mi + 1]) mi++;
      int local = idx - ds.cum[mi];
      WDesc d = ds.d[mi];
      int lane = local & 63;
      int rest = local >> 6;
      int t = rest % d.T;
      int kb = rest / d.T;
      int m = lane & 15, quad = lane >> 4;
      int col = t * 16 + m;
      short8 v;
      for (int j = 0; j < 8; ++j) {
        int k = kb * 32 + quad * 8 + j;
        if (col < d.ncols) {
          int off = k * d.ncols + col;
          v[j] = f32 ? (short)f2bf(((const float*)d.W)[off])
                     : (short)((const unsigned short*)d.W)[off];
        } else {
          v[j] = 0;
        }
      }
      *(short8*)(d.F + (size_t)local * 8) = v;
    } else if (b < 41) {  // param convert
      PCv p = P.a[b - 24];
      for (int i = tid; i < p.cap; i += 512) {
        unsigned short o = 0;
        if (i < p.n)
          o = f32 ? f2bf(((const float*)p.s)[i]) : ((const unsigned short*)p.s)[i];
        p.d[i] = o;
      }
    } else {  // flags
      if (tid < 64) {
        int i64 = probe_i64(ei);
        if (tid == 0) {
          flags[0] = i64;
          flags[1] = f32;
          flags[2] = 0;
        }
      }
    }
    return;
  }
  int tid = threadIdx.x;
  if (tid < NBUCK) lhist[tid] = 0;
  int i64 = probe_i64(ei);
  __syncthreads();
  int e0 = blockIdx.x * EPB;
  int e1 = e0 + EPB; if (e1 > EE) e1 = EE;
  // phase 1: local histogram of dst bins
  for (int e = e0 + tid; e < e1; e += 512) {
    int d = i64 ? (int)((const long long*)ei)[EE + e] : ((const int*)ei)[EE + e];
    d = d < 0 ? 0 : (d >= NN ? NN - 1 : d);
    atomicAdd(&lhist[d >> 8], 1);
  }
  __syncthreads();
  // phase 2: one global reservation per bin
  if (tid < NBUCK) {
    int c = lhist[tid];
    lbase[tid] = c ? atomicAdd(&bcur[tid * 16], c) : 0;  // cursors padded to 64B
    lhist[tid] = 0;                                      // reuse as local cursor
  }
  __syncthreads();
  // phase 3: ranked scatter
  for (int e = e0 + tid; e < e1; e += 512) {
    int s, d;
    if (i64) {
      s = (int)((const long long*)ei)[e];
      d = (int)((const long long*)ei)[EE + e];
    } else {
      s = ((const int*)ei)[e];
      d = ((const int*)ei)[EE + e];
    }
    s = s < 0 ? 0 : (s >= NN ? NN - 1 : s);
    d = d < 0 ? 0 : (d >= NN ? NN - 1 : d);
    int bin = d >> 8;
    int r = atomicAdd(&lhist[bin], 1);
    int pos = lbase[bin] + r;
    if (pos < BCAP)
      bedges[(size_t)bin * BCAP + pos] =
          ((unsigned int)(d & 0xFF) << 24) | ((unsigned int)s << 8);
  }
}

// ---------------- fused pass 2: per-bucket dst sort (blocks < NBUCK) || 3-set GEMM ----
// GEMM waves read each x row ONCE and produce ident, bxl, bxr (3 sets) from the
// same A fragment — single 25.6 MB x pass instead of two.
__global__ __launch_bounds__(512) void fused_sort_gemm(
    const unsigned int* __restrict__ bedges, const int* __restrict__ bcur,
    int* __restrict__ offs, int* __restrict__ src_sorted,
    const void* __restrict__ A, const int* __restrict__ flagp, GArgs g,
    int nset, int M, int T, int ncols) {
  __shared__ int lhist[256];
  __shared__ int lscan[256];
  __shared__ int lbin[256];
  __shared__ int sbase, scount, stotal;
  __shared__ unsigned int le[BCAP];
  __shared__ unsigned short lrank[BCAP];
  if (blockIdx.x >= NBUCK) {
    int wave = (blockIdx.x - NBUCK) * 8 + (threadIdx.x >> 6);
    gemm_body(wave, threadIdx.x & 63, A, *flagp, g, nset, M, T, ncols);
    return;
  }
  int k = blockIdx.x;
  int tid = threadIdx.x;
  if (tid < 256) {
    int c = 0;
    if (tid < NBUCK) {
      int v = bcur[tid * 16];
      c = v < BCAP ? v : BCAP;
    }
    lscan[tid] = c;
  }
  __syncthreads();
  for (int off = 1; off < 256; off <<= 1) {
    int u = 0;
    if (tid < 256 && tid >= off) u = lscan[tid - off];
    __syncthreads();
    if (tid < 256) lscan[tid] += u;
    __syncthreads();
  }
  if (tid == 0) {
    int pb = (k == 0) ? 0 : lscan[k - 1];
    sbase = pb;
    scount = lscan[k] - pb;
    stotal = lscan[NBUCK - 1];
  }
  if (tid < 256) lhist[tid] = 0;
  __syncthreads();
  int base = sbase, count = scount;
  const unsigned int* myb = bedges + (size_t)k * BCAP;
  for (int i = tid; i < count; i += 512) {
    unsigned int pk = myb[i];
    int bin = pk >> 24;
    int r = atomicAdd(&lhist[bin], 1);
    le[i] = pk;
    lrank[i] = (unsigned short)r;
  }
  __syncthreads();
  int hc = 0;
  if (tid < 256) {
    hc = lhist[tid];
    lscan[tid] = hc;
  }
  __syncthreads();
  for (int off = 1; off < 256; off <<= 1) {
    int u = 0;
    if (tid < 256 && tid >= off) u = lscan[tid - off];
    __syncthreads();
    if (tid < 256) lscan[tid] += u;
    __syncthreads();
  }
  if (tid < 256) {
    int binoff = lscan[tid] - hc;  // exclusive within bucket
    lbin[tid] = binoff;
    int node = k * 256 + tid;
    if (node < NN) offs[node] = base + binoff;
    if (k == 0 && tid == 0) offs[NN] = stotal;
  }
  __syncthreads();
  for (int i = tid; i < count; i += 512) {
    unsigned int pk = le[i];
    int bin = pk >> 24;
    int pos = base + lbin[bin] + (int)lrank[i];
    src_sorted[pos] = (int)(pk & 0x00FFFF00u);  // src<<8 byte offset
  }
}

// ---------------- edge aggregation, hidden layers (H=4, C=32) ----------------
// Main loop at the compulsory cross-XCD L2-fill roofline (~90 MB @ ~2.3 TB/s);
// whole kernel within 2% of its 129 MB / 2.3 TB/s traffic floor — do not touch.
// 512 threads / 8 waves / 16 dsts per block; fused next-layer GEMM epilogue on
// a full 16x128 LDS tile (272B stride = conflict-free).
template <int TT, int NCOLS, int WRITEX>
__global__ __launch_bounds__(512) void edge_hid_kernel(
    const unsigned short* __restrict__ xl, const unsigned short* __restrict__ xr,
    const unsigned short* __restrict__ att, const unsigned short* __restrict__ bias,
    const unsigned short* __restrict__ gamma, const unsigned short* __restrict__ beta,
    const unsigned short* __restrict__ resid, unsigned short* __restrict__ xout,
    const int* __restrict__ offs, const int* __restrict__ srcs,
    const unsigned short* __restrict__ Fl, const unsigned short* __restrict__ Fr,
    const unsigned short* __restrict__ bl, const unsigned short* __restrict__ br,
    unsigned short* __restrict__ outl, unsigned short* __restrict__ outr) {
  __shared__ unsigned short sA[16 * 136];  // 16 real rows, 272B stride (+pad)
  const int wid = threadIdx.x >> 6;
  int wpair = blockIdx.x * 8 + wid;
  int lane = threadIdx.x & 63;
  int half = lane >> 5;
  int wv = wpair * 2 + half;
  // NN % 16 == 0 and grid covers it exactly -> no early returns,
  // so the epilogue __syncthreads below is safe.
  int hl = lane & 31;
  int sub = hl >> 4;          // edge slot (0/1) within this half
  int cb = (hl & 15) * 16;    // byte offset of this lane's 8 channels (256 B/row)
  int beg = offs[wv], end = offs[wv + 1], last = end - 1;
  int iters = (end - beg + 1) >> 1;  // ceil(deg/2)
  int oi = __shfl_xor(iters, 32);
  int maxit = __builtin_amdgcn_readfirstlane(iters > oi ? iters : oi);
  const char* xlb = (const char*)xl;
  int c0 = hl * 4;
  // hoisted epilogue load: resid row latency hides under the whole edge loop
  uint2 rr = *(const uint2*)(resid + (size_t)wv * 128 + c0);
  uint4 xr8 = *(const uint4*)((const char*)xr + (size_t)wv * 256 + cb);
  float rx0 = blo(xr8.x), rx1 = bhi(xr8.x), rx2 = blo(xr8.y), rx3 = bhi(xr8.y);
  float rx4 = blo(xr8.z), rx5 = bhi(xr8.z), rx6 = blo(xr8.w), rx7 = bhi(xr8.w);
  uint4 at8 = *(const uint4*)((const char*)att + cb);
  float a0 = blo(at8.x), a1 = bhi(at8.x), a2 = blo(at8.y), a3 = bhi(at8.y);
  float a4 = blo(at8.z), a5 = bhi(at8.z), a6 = blo(at8.w), a7 = bhi(at8.w);
  float acc0 = 0.f, acc1 = 0.f, acc2 = 0.f, acc3 = 0.f;
  float acc4 = 0.f, acc5 = 0.f, acc6 = 0.f, acc7 = 0.f, den = 0.f;
  // pipeline prologue: index for edge 0 and edge 1, gather for edge 0
  int ir = beg + sub;
  int o_cur = srcs[clampe(ir, last)];
  int o_nxt = srcs[clampe(ir + 2, last)];
  uint4 u = *(const uint4*)(xlb + (o_cur + cb));
  for (int it = 0; it < maxit; ++it) {
    int o_p = srcs[clampe(ir + 4, last)];
    uint4 un = *(const uint4*)(xlb + (o_nxt + cb));
    float mk = (ir <= last) ? 1.f : 0.f;
    ir += 2;
    float x0 = blo(u.x), x1 = bhi(u.x), x2 = blo(u.y), x3 = bhi(u.y);
    float x4 = blo(u.z), x5 = bhi(u.z), x6 = blo(u.w), x7 = bhi(u.w);
    float t0 = x0 + rx0, t1 = x1 + rx1, t2 = x2 + rx2, t3 = x3 + rx3;
    float t4 = x4 + rx4, t5 = x5 + rx5, t6 = x6 + rx6, t7 = x7 + rx7;
    float pa = a0 * t0;
    pa = fmaf(a1, t1, pa); pa = fmaf(a2, t2, pa); pa = fmaf(a3, t3, pa);
    pa = fmaf(a4, t4, pa); pa = fmaf(a5, t5, pa); pa = fmaf(a6, t6, pa); pa = fmaf(a7, t7, pa);
    float pb = a0 * fabsf(t0);
    pb = fmaf(a1, fabsf(t1), pb); pb = fmaf(a2, fabsf(t2), pb); pb = fmaf(a3, fabsf(t3), pb);
    pb = fmaf(a4, fabsf(t4), pb); pb = fmaf(a5, fabsf(t5), pb);
    pb = fmaf(a6, fabsf(t6), pb); pb = fmaf(a7, fabsf(t7), pb);
    float p = fmaf(0.4f, pb, 0.6f * pa);
    p = dpp_add<0xB1>(p);  // quad xor1
    p = dpp_add<0x4E>(p);  // quad xor2 -> 4-lane head sum (32 ch)
    float w = __expf(fminf(p, 60.f)) * mk;
    den += w;
    acc0 = fmaf(w, x0, acc0); acc1 = fmaf(w, x1, acc1);
    acc2 = fmaf(w, x2, acc2); acc3 = fmaf(w, x3, acc3);
    acc4 = fmaf(w, x4, acc4); acc5 = fmaf(w, x5, acc5);
    acc6 = fmaf(w, x6, acc6); acc7 = fmaf(w, x7, acc7);
    u = un;
    o_nxt = o_p;
  }
  // merge the two edge slots within each half (xor16 stays inside the half)
  den += __shfl_xor(den, 16);
  acc0 += __shfl_xor(acc0, 16); acc1 += __shfl_xor(acc1, 16);
  acc2 += __shfl_xor(acc2, 16); acc3 += __shfl_xor(acc3, 16);
  acc4 += __shfl_xor(acc4, 16); acc5 += __shfl_xor(acc5, 16);
  acc6 += __shfl_xor(acc6, 16); acc7 += __shfl_xor(acc7, 16);
  // redistribute to 4 ch/lane within each half (32 lanes per dst)
  int srcLane = (half << 5) + (hl >> 1);
  float b0 = __shfl(acc0, srcLane), b1 = __shfl(acc1, srcLane);
  float b2 = __shfl(acc2, srcLane), b3 = __shfl(acc3, srcLane);
  float h4 = __shfl(acc4, srcLane), h5 = __shfl(acc5, srcLane);
  float h6 = __shfl(acc6, srcLane), h7 = __shfl(acc7, srcLane);
  float dn = __shfl(den, srcLane);
  bool hi = (hl & 1) != 0;
  float v0 = hi ? h4 : b0, v1 = hi ? h5 : b1, v2 = hi ? h6 : b2, v3 = hi ? h7 : b3;
  float inv = __builtin_amdgcn_rcpf(dn + 1e-16f);
  uint2 bb = *(const uint2*)(bias + c0);
  float o0 = v0 * inv + blo(bb.x), o1 = v1 * inv + bhi(bb.x);
  float o2 = v2 * inv + blo(bb.y), o3 = v3 * inv + bhi(bb.y);
  // LayerNorm over 128 ch: 32-lane reduction within each half
  float s = (o0 + o1) + (o2 + o3);
  for (int k = 1; k < 32; k <<= 1) s += __shfl_xor(s, k);
  float mu = s * (1.f / 128.f);
  float d0 = o0 - mu, d1 = o1 - mu, d2 = o2 - mu, d3 = o3 - mu;
  float q = (d0 * d0 + d1 * d1) + (d2 * d2 + d3 * d3);
  for (int k = 1; k < 32; k <<= 1) q += __shfl_xor(q, k);
  float rstd = rsqrtf(q * (1.f / 128.f) + 1e-5f);
  uint2 gg = *(const uint2*)(gamma + c0);
  uint2 be = *(const uint2*)(beta + c0);
  float y0 = d0 * rstd * blo(gg.x) + blo(be.x);
  float y1 = d1 * rstd * bhi(gg.x) + bhi(be.x);
  float y2 = d2 * rstd * blo(gg.y) + blo(be.y);
  float y3 = d3 * rstd * bhi(gg.y) + bhi(be.y);
  y0 = gelu1(y0); y1 = gelu1(y1); y2 = gelu1(y2); y3 = gelu1(y3);
  y0 += blo(rr.x); y1 += bhi(rr.x); y2 += blo(rr.y); y3 += bhi(rr.y);
  uint2 pk;
  pk.x = (unsigned int)f2bf(y0) | ((unsigned int)f2bf(y1) << 16);
  pk.y = (unsigned int)f2bf(y2) | ((unsigned int)f2bf(y3) << 16);
  if (WRITEX) *(uint2*)(xout + (size_t)wv * 128 + c0) = pk;

  // ---- fused row-local GEMM epilogue: Out{l,r}[row] = x_row @ W{l,r} + b ----
  int lrow = wid * 2 + half;                 // 0..15 local row = full MFMA tile
  *(uint2*)(&sA[lrow * 136 + c0]) = pk;      // stage bf16 row (272B stride)
  __syncthreads();
  int m = lane & 15, quad = lane >> 4;
  const unsigned short* arow = sA + m * 136 + quad * 8;
  short8 A0 = *(const short8*)(arow);
  short8 A1 = *(const short8*)(arow + 32);
  short8 A2 = *(const short8*)(arow + 64);
  short8 A3 = *(const short8*)(arow + 96);
  const size_t kst = (size_t)TT * 64 * 8;
  const int rowbase = blockIdx.x * 16;
  constexpr int PER = (2 * TT) / 8;  // tile-columns per wave (l and r mats)
#pragma unroll
  for (int jj = 0; jj < PER; ++jj) {
    int j = wid * PER + jj;
    bool isr = j >= TT;
    const unsigned short* F = isr ? Fr : Fl;
    const unsigned short* bs = isr ? br : bl;
    unsigned short* Out = isr ? outr : outl;
    int t = isr ? j - TT : j;
    floatx4 acc = {0.f, 0.f, 0.f, 0.f};
    const unsigned short* wp = F + ((size_t)t * 64 + lane) * 8;
    acc = __builtin_amdgcn_mfma_f32_16x16x32_bf16(A0, *(const short8*)(wp), acc, 0, 0, 0);
    acc = __builtin_amdgcn_mfma_f32_16x16x32_bf16(A1, *(const short8*)(wp + kst), acc, 0, 0, 0);
    acc = __builtin_amdgcn_mfma_f32_16x16x32_bf16(A2, *(const short8*)(wp + 2 * kst), acc, 0, 0, 0);
    acc = __builtin_amdgcn_mfma_f32_16x16x32_bf16(A3, *(const short8*)(wp + 3 * kst), acc, 0, 0, 0);
    int col = t * 16 + m;
    float bbv = bf2f(bs[col]);
#pragma unroll
    for (int r = 0; r < 4; ++r)
      Out[(size_t)(rowbase + quad * 4 + r) * NCOLS + col] = f2bf(acc[r] + bbv);
  }
}

// ---------------- edge aggregation, output layer (padded to 64 ch) ----------------
__global__ __launch_bounds__(256) void edge_out_kernel(
    const unsigned short* __restrict__ xl, const unsigned short* __restrict__ xr,
    const unsigned short* __restrict__ att, const unsigned short* __restrict__ bias,
    void* __restrict__ out, const int* __restrict__ flagp,
    const int* __restrict__ offs, const int* __restrict__ srcs) {
  int wv = blockIdx.x * 4 + (threadIdx.x >> 6);
  if (wv >= NN) return;
  int lane = threadIdx.x & 63;
  int oct = lane >> 3;
  int cb = (lane & 7) * 16;  // byte offset of 8 ch (8 lanes x 16B = 128B row)
  int beg = __builtin_amdgcn_readfirstlane(offs[wv]);
  int last = __builtin_amdgcn_readfirstlane(offs[wv + 1]) - 1;
  const char* xlb = (const char*)xl;
  uint4 xr8 = *(const uint4*)((const char*)xr + (size_t)wv * 128 + cb);
  float rx0 = blo(xr8.x), rx1 = bhi(xr8.x), rx2 = blo(xr8.y), rx3 = bhi(xr8.y);
  float rx4 = blo(xr8.z), rx5 = bhi(xr8.z), rx6 = blo(xr8.w), rx7 = bhi(xr8.w);
  uint4 at8 = *(const uint4*)((const char*)att + cb);
  float a0 = blo(at8.x), a1 = bhi(at8.x), a2 = blo(at8.y), a3 = bhi(at8.y);
  float a4 = blo(at8.z), a5 = bhi(at8.z), a6 = blo(at8.w), a7 = bhi(at8.w);
  float acc0 = 0.f, acc1 = 0.f, acc2 = 0.f, acc3 = 0.f;
  float acc4 = 0.f, acc5 = 0.f, acc6 = 0.f, acc7 = 0.f, den = 0.f;
  // pipeline prologue
  int ir = beg + oct;
  int o_cur = srcs[clampe(ir, last)];
  int o_nxt = srcs[clampe(ir + 8, last)];
  uint4 u = *(const uint4*)(xlb + ((o_cur >> 1) + cb));  // 64-ch rows = 128 B
  for (int e = beg; e <= last; e += 8) {
    int o_p = srcs[clampe(ir + 16, last)];
    uint4 un = *(const uint4*)(xlb + ((o_nxt >> 1) + cb));
    float mk = (ir <= last) ? 1.f : 0.f;
    ir += 8;
    float x0 = blo(u.x), x1 = bhi(u.x), x2 = blo(u.y), x3 = bhi(u.y);
    float x4 = blo(u.z), x5 = bhi(u.z), x6 = blo(u.w), x7 = bhi(u.w);
    float t0 = x0 + rx0, t1 = x1 + rx1, t2 = x2 + rx2, t3 = x3 + rx3;
    float t4 = x4 + rx4, t5 = x5 + rx5, t6 = x6 + rx6, t7 = x7 + rx7;
    float pa = a0 * t0;
    pa = fmaf(a1, t1, pa); pa = fmaf(a2, t2, pa); pa = fmaf(a3, t3, pa);
    pa = fmaf(a4, t4, pa); pa = fmaf(a5, t5, pa); pa = fmaf(a6, t6, pa); pa = fmaf(a7, t7, pa);
    float pb = a0 * fabsf(t0);
    pb = fmaf(a1, fabsf(t1), pb); pb = fmaf(a2, fabsf(t2), pb); pb = fmaf(a3, fabsf(t3), pb);
    pb = fmaf(a4, fabsf(t4), pb); pb = fmaf(a5, fabsf(t5), pb);
    pb = fmaf(a6, fabsf(t6), pb); pb = fmaf(a7, fabsf(t7), pb);
    float p = fmaf(0.4f, pb, 0.6f * pa);
    p = dpp_add<0xB1>(p);   // xor1
    p = dpp_add<0x4E>(p);   // xor2
    p = dpp_add<0x141>(p);  // row_half_mirror -> 8-lane sum = 64-ch dot
    float w = __expf(fminf(p, 60.f)) * mk;
    den += w;
    acc0 = fmaf(w, x0, acc0); acc1 = fmaf(w, x1, acc1);
    acc2 = fmaf(w, x2, acc2); acc3 = fmaf(w, x3, acc3);
    acc4 = fmaf(w, x4, acc4); acc5 = fmaf(w, x5, acc5);
    acc6 = fmaf(w, x6, acc6); acc7 = fmaf(w, x7, acc7);
    u = un;
    o_nxt = o_p;
  }
  // merge the eight octets
  den += __shfl_xor(den, 8);  den += __shfl_xor(den, 16);  den += __shfl_xor(den, 32);
  acc0 += __shfl_xor(acc0, 8); acc0 += __shfl_xor(acc0, 16); acc0 += __shfl_xor(acc0, 32);
  acc1 += __shfl_xor(acc1, 8); acc1 += __shfl_xor(acc1, 16); acc1 += __shfl_xor(acc1, 32);
  acc2 += __shfl_xor(acc2, 8); acc2 += __shfl_xor(acc2, 16); acc2 += __shfl_xor(acc2, 32);
  acc3 += __shfl_xor(acc3, 8); acc3 += __shfl_xor(acc3, 16); acc3 += __shfl_xor(acc3, 32);
  acc4 += __shfl_xor(acc4, 8); acc4 += __shfl_xor(acc4, 16); acc4 += __shfl_xor(acc4, 32);
  acc5 += __shfl_xor(acc5, 8); acc5 += __shfl_xor(acc5, 16); acc5 += __shfl_xor(acc5, 32);
  acc6 += __shfl_xor(acc6, 8); acc6 += __shfl_xor(acc6, 16); acc6 += __shfl_xor(acc6, 32);
  acc7 += __shfl_xor(acc7, 8); acc7 += __shfl_xor(acc7, 16); acc7 += __shfl_xor(acc7, 32);
  float inv = __builtin_amdgcn_rcpf(den + 1e-16f);
  if (lane < 5) {  // lanes 0..4 cover channels 0..39
    uint4 bb = *(const uint4*)((const char*)bias + cb);
    float v0 = acc0 * inv + blo(bb.x), v1 = acc1 * inv + bhi(bb.x);
    float v2 = acc2 * inv + blo(bb.y), v3 = acc3 * inv + bhi(bb.y);
    float v4 = acc4 * inv + blo(bb.z), v5 = acc5 * inv + bhi(bb.z);
    float v6 = acc6 * inv + blo(bb.w), v7 = acc7 * inv + bhi(bb.w);
    int c0 = lane * 8;
    if (*flagp) {
      float* op = (float*)out + (size_t)wv * OUTD + c0;
      float4 f0 = {v0, v1, v2, v3};
      float4 f1 = {v4, v5, v6, v7};
      *(float4*)(op) = f0;
      *(float4*)(op + 4) = f1;
    } else {
      uint4 pk;
      pk.x = (unsigned int)f2bf(v0) | ((unsigned int)f2bf(v1) << 16);
      pk.y = (unsigned int)f2bf(v2) | ((unsigned int)f2bf(v3) << 16);
      pk.z = (unsigned int)f2bf(v4) | ((unsigned int)f2bf(v5) << 16);
      pk.w = (unsigned int)f2bf(v6) | ((unsigned int)f2bf(v7) << 16);
      *(uint4*)((unsigned short*)out + (size_t)wv * OUTD + c0) = pk;
    }
  }
}

extern "C" void kernel_launch(void* const* d_in, const int* in_sizes, int n_in,
                              void* d_out, int out_size, void* d_ws, size_t ws_size,
                              hipStream_t stream) {
  const void* x = d_in[0];
  const void* ei = d_in[1];

  char* ws = (char*)d_ws;
  size_t o = 0;
  auto alloc = [&](size_t bytes) {
    void* p = ws + o;
    o = (o + bytes + 255) & ~(size_t)255;
    return p;
  };
  int* flags = (int*)alloc(256);
  int* src_sorted = (int*)alloc((size_t)EE * 4);
  int* offs = (int*)alloc((size_t)(NN + 1) * 4);
  int* bcur = (int*)alloc((size_t)NBUCK * 16 * 4);
  unsigned int* bedges = (unsigned int*)alloc((size_t)NBUCK * BCAP * 4);
  unsigned short* F_W0 = (unsigned short*)alloc(2048 * 16);
  unsigned short* F_W1l = (unsigned short*)alloc(2048 * 16);
  unsigned short* F_W1r = (unsigned short*)alloc(2048 * 16);
  unsigned short* F_W2l = (unsigned short*)alloc(2048 * 16);
  unsigned short* F_W2r = (unsigned short*)alloc(2048 * 16);
  unsigned short* F_W3l = (unsigned short*)alloc(1024 * 16);
  unsigned short* F_W3r = (unsigned short*)alloc(1024 * 16);
  unsigned short* pblk = (unsigned short*)alloc(4096);
  unsigned short* ident = (unsigned short*)alloc((size_t)NN * 128 * 2);  // x0 -> x1
  unsigned short* bxlA = (unsigned short*)alloc((size_t)NN * 128 * 2);
  unsigned short* bxrA = (unsigned short*)alloc((size_t)NN * 128 * 2);
  unsigned short* bxlB = (unsigned short*)alloc((size_t)NN * 128 * 2);
  unsigned short* bxrB = (unsigned short*)alloc((size_t)NN * 128 * 2);
  (void)ws_size;

  unsigned short* pb0 = pblk;
  unsigned short* pb1l = pblk + 128;
  unsigned short* pb1r = pblk + 256;
  unsigned short* patt1 = pblk + 384;
  unsigned short* pbias1 = pblk + 512;
  unsigned short* pg1 = pblk + 640;
  unsigned short* pbe1 = pblk + 768;
  unsigned short* pb2l = pblk + 896;
  unsigned short* pb2r = pblk + 1024;
  unsigned short* patt2 = pblk + 1152;
  unsigned short* pbias2 = pblk + 1280;
  unsigned short* pg2 = pblk + 1408;
  unsigned short* pbe2 = pblk + 1536;
  unsigned short* pb3l = pblk + 1664;   // cap 64 (zero-padded)
  unsigned short* pb3r = pblk + 1728;   // cap 64
  unsigned short* patt3 = pblk + 1792;  // cap 64
  unsigned short* pbias3 = pblk + 1856; // cap 64

  WDescs wd;
  wd.d[0] = {d_in[2], F_W0, 8, 128};
  wd.d[1] = {d_in[4], F_W1l, 8, 128};
  wd.d[2] = {d_in[6], F_W1r, 8, 128};
  wd.d[3] = {d_in[12], F_W2l, 8, 128};
  wd.d[4] = {d_in[14], F_W2r, 8, 128};
  wd.d[5] = {d_in[20], F_W3l, 4, 40};  // T=4 -> 64 padded cols
  wd.d[6] = {d_in[22], F_W3r, 4, 40};
  int cum[8] = {0, 2048, 4096, 6144, 8192, 10240, 11264, 12288};
  for (int i = 0; i < 8; ++i) wd.cum[i] = cum[i];
  PCvs P;
  P.a[0] = {d_in[3], pb0, 128, 128};
  P.a[1] = {d_in[5], pb1l, 128, 128};
  P.a[2] = {d_in[7], pb1r, 128, 128};
  P.a[3] = {d_in[8], patt1, 128, 128};
  P.a[4] = {d_in[9], pbias1, 128, 128};
  P.a[5] = {d_in[10], pg1, 128, 128};
  P.a[6] = {d_in[11], pbe1, 128, 128};
  P.a[7] = {d_in[13], pb2l, 128, 128};
  P.a[8] = {d_in[15], pb2r, 128, 128};
  P.a[9] = {d_in[16], patt2, 128, 128};
  P.a[10] = {d_in[17], pbias2, 128, 128};
  P.a[11] = {d_in[18], pg2, 128, 128};
  P.a[12] = {d_in[19], pbe2, 128, 128};
  P.a[13] = {d_in[21], pb3l, 40, 64};
  P.a[14] = {d_in[23], pb3r, 40, 64};
  P.a[15] = {d_in[24], patt3, 40, 64};
  P.a[16] = {d_in[25], pbias3, 40, 64};

  const int* fx = flags + 1;
  const int gb8 = (NN + 127) / 128;   // 391 blocks, 8 waves each, 16 rows/wave
  const int eb = (NN + 3) / 4;        // 12500 blocks, 1 wave/dst (edge_out)
  const int eb16 = NN / 16;           // 3125 blocks, 16 dsts/block (edge_hid)

  // ---- zero bucket cursors (graph-capture-safe) ----
  hipMemsetAsync(bcur, 0, (size_t)NBUCK * 16 * 4, stream);

  // ---- fused pass 1: edge bucket scatter || weight/param convert + flags ----
  fused_scatter_init<<<ABLKS + 42, 512, 0, stream>>>(ei, x, bedges, bcur, flags, wd, P);

  // ---- fused pass 2: per-bucket sort || 3-set GEMM (x read ONCE ->
  //      ident = x@W0, bxlA = x@W1l, bxrA = x@W1r) ----
  GArgs g1a;
  g1a.s[0] = {F_W0, pb0, ident};
  g1a.s[1] = {F_W1l, pb1l, bxlA};
  g1a.s[2] = {F_W1r, pb1r, bxrA};
  fused_sort_gemm<<<NBUCK + gb8, 512, 0, stream>>>(bedges, bcur, offs, src_sorted, x,
                                                   fx, g1a, 3, NN, 8, 128);

  // ---- layer 1 aggregation + fused layer-2 GEMM (reads A pair, writes B pair) ----
  edge_hid_kernel<8, 128, 1><<<eb16, 512, 0, stream>>>(
      bxlA, bxrA, patt1, pbias1, pg1, pbe1, ident, ident, offs, src_sorted,
      F_W2l, F_W2r, pb2l, pb2r, bxlB, bxrB);

  // ---- layer 2 aggregation + fused layer-3 GEMM (reads B pair, writes A pair) ----
  edge_hid_kernel<4, 64, 0><<<eb16, 512, 0, stream>>>(
      bxlB, bxrB, patt2, pbias2, pg2, pbe2, ident, ident, offs, src_sorted,
      F_W3l, F_W3r, pb3l, pb3r, bxlA, bxrA);

  // ---- layer 3 aggregation (64-ch padded rows in A pair) ----
  edge_out_kernel<<<eb, 256, 0, stream>>>(bxlA, bxrA, patt3, pbias3, d_out, fx, offs,
                                          src_sorted);
}